// Round 2
// baseline (339.714 us; speedup 1.0000x reference)
//
#include <hip/hip_runtime.h>

typedef unsigned short ushort_t;
typedef __attribute__((ext_vector_type(8))) short short8;
typedef __attribute__((ext_vector_type(8))) __bf16 bf16x8;
typedef __attribute__((ext_vector_type(4))) float float4v;
typedef __attribute__((ext_vector_type(4))) unsigned int uint4v;

// ---------- bf16 helpers ----------
__device__ __forceinline__ float bf2f(ushort_t u) {
    unsigned int v = ((unsigned int)u) << 16;
    return __builtin_bit_cast(float, v);
}
__device__ __forceinline__ ushort_t f2bf(float f) {
    unsigned int u = __builtin_bit_cast(unsigned int, f);
    unsigned int lsb = (u >> 16) & 1u;
    u += 0x7fffu + lsb;  // round-to-nearest-even
    return (ushort_t)(u >> 16);
}
__device__ __forceinline__ uint4v pack8(const ushort_t* r) {
    uint4v u;
#pragma unroll
    for (int i = 0; i < 4; ++i)
        u[i] = (unsigned int)r[2 * i] | ((unsigned int)r[2 * i + 1] << 16);
    return u;
}
__device__ __forceinline__ void unpack8(uint4v u, float* f) {
#pragma unroll
    for (int i = 0; i < 4; ++i) {
        unsigned int x = u[i];
        f[2 * i] = __builtin_bit_cast(float, x << 16);
        f[2 * i + 1] = __builtin_bit_cast(float, x & 0xffff0000u);
    }
}
__device__ __forceinline__ uint4v ld8f32_bf(const float* p) {
    float4v a = *(const float4v*)p;
    float4v b = *(const float4v*)(p + 4);
    ushort_t r[8];
#pragma unroll
    for (int j = 0; j < 4; ++j) { r[j] = f2bf(a[j]); r[4 + j] = f2bf(b[j]); }
    return pack8(r);
}

// ---------- async global->LDS (16B per lane, dest = uniform base + lane*16) ----------
#if __has_builtin(__builtin_amdgcn_global_load_lds)
#define HAVE_GLDS 1
__device__ __forceinline__ void glds16(const ushort_t* gp, ushort_t* lp) {
    __builtin_amdgcn_global_load_lds((const __attribute__((address_space(1))) void*)gp,
                                     (__attribute__((address_space(3))) void*)lp, 16, 0, 0);
}
#else
#define HAVE_GLDS 0
#endif

// ---------- MFMA hedge ----------
template <typename V>
__device__ __forceinline__ auto mfma_sel(V a, V b, float4v c, int)
    -> decltype(__builtin_amdgcn_mfma_f32_16x16x32_bf16(a, b, c, 0, 0, 0)) {
    return __builtin_amdgcn_mfma_f32_16x16x32_bf16(a, b, c, 0, 0, 0);
}
template <typename V>
__device__ __forceinline__ float4v mfma_sel(V a, V b, float4v c, long) {
    return __builtin_amdgcn_mfma_f32_16x16x32_bf16(__builtin_bit_cast(bf16x8, a),
                                                   __builtin_bit_cast(bf16x8, b), c, 0, 0, 0);
}
__device__ __forceinline__ float4v mfma_bf16(short8 a, short8 b, float4v c) {
    return mfma_sel(a, b, c, 0);
}

__device__ __forceinline__ float wave_sum(float v) {
#pragma unroll
    for (int o = 32; o; o >>= 1) v += __shfl_xor(v, o);
    return v;
}

// ---------- constants ----------
#define HIDDEN 2880
#define NTOK 2048
#define QKV_DIM 5120
#define ATTN_DIM 4096
#define SM_SCALE 0.125f

// ---------- fp32 -> bf16 bulk convert (dual source in one launch) ----------
__global__ __launch_bounds__(256) void f32_to_bf16_dual_kernel(const float* __restrict__ a,
                                                               ushort_t* __restrict__ ao, int na8,
                                                               const float* __restrict__ b,
                                                               ushort_t* __restrict__ bo, int nb8) {
    int idx = blockIdx.x * 256 + threadIdx.x;
    if (idx < na8) {
        *(uint4v*)(ao + (size_t)idx * 8) = ld8f32_bf(a + (size_t)idx * 8);
    } else {
        int j = idx - na8;
        if (j < nb8) *(uint4v*)(bo + (size_t)j * 8) = ld8f32_bf(b + (size_t)j * 8);
    }
}

// ---------- RMSNorm: fp32 x -> bf16 normed ----------
__global__ __launch_bounds__(256) void rmsnorm_kernel(const float* __restrict__ x,
                                                      const float* __restrict__ wgt,
                                                      ushort_t* __restrict__ out) {
    const int tok = blockIdx.x, tid = threadIdx.x;
    const float* xr = x + (size_t)tok * HIDDEN;
    float v[16];
    float ss = 0.f;
#pragma unroll
    for (int i = 0; i < 2; ++i) {
        int c = tid + i * 256;
        if (c < 360) {
            float4v a = *(const float4v*)(xr + c * 8);
            float4v b = *(const float4v*)(xr + c * 8 + 4);
#pragma unroll
            for (int j = 0; j < 4; ++j) { v[i * 8 + j] = a[j]; v[i * 8 + 4 + j] = b[j]; }
#pragma unroll
            for (int j = 0; j < 8; ++j) ss += v[i * 8 + j] * v[i * 8 + j];
        }
    }
    ss = wave_sum(ss);
    __shared__ float red[4];
    if ((tid & 63) == 0) red[tid >> 6] = ss;
    __syncthreads();
    float scale = rsqrtf((red[0] + red[1] + red[2] + red[3]) * (1.f / 2880.f) + 1e-5f);
#pragma unroll
    for (int i = 0; i < 2; ++i) {
        int c = tid + i * 256;
        if (c < 360) {
            float4v wa = *(const float4v*)(wgt + c * 8);
            float4v wb = *(const float4v*)(wgt + c * 8 + 4);
            ushort_t r[8];
#pragma unroll
            for (int j = 0; j < 4; ++j) {
                r[j] = f2bf(v[i * 8 + j] * scale * wa[j]);
                r[4 + j] = f2bf(v[i * 8 + 4 + j] * scale * wb[j]);
            }
            *(uint4v*)(out + (size_t)tok * HIDDEN + c * 8) = pack8(r);
        }
    }
}

// ---------- RoPE apply, YaRN cos/sin on the fly ----------
__global__ __launch_bounds__(256) void rope_apply_kernel(ushort_t* __restrict__ qkv) {
    int idx = blockIdx.x * 256 + threadIdx.x;  // 2048 * 72 * 4
    int tok = idx / 288;
    int rem = idx - tok * 288;
    int h = rem >> 2, dg = rem & 3;
    int s = tok & 1023;
    size_t base = (size_t)tok * QKV_DIM + (h < 64 ? h * 64 : 4096 + (h - 64) * 64) + dg * 8;
    uint4v u1 = *(const uint4v*)(qkv + base);
    uint4v u2 = *(const uint4v*)(qkv + base + 32);
    float f1[8], f2[8];
    unpack8(u1, f1);
    unpack8(u2, f2);
    const float step = (float)(11.918390573078392 / 32.0);
    const float conc = (float)(1.3465735902799727);
    const float low = (float)(8.092890725542669);
    const float invden = (float)(1.0 / 9.305804387286162);
    ushort_t r1[8], r2[8];
#pragma unroll
    for (int jj = 0; jj < 8; ++jj) {
        int j = dg * 8 + jj;
        float invf = __expf(-(float)j * step);
        float ramp = ((float)j - low) * invden;
        float mask = 1.f - fminf(fmaxf(ramp, 0.f), 1.f);
        float inv_freq = invf * ((1.f - mask) * 0.03125f + mask);
        float ang = (float)s * inv_freq;
        float c = cosf(ang) * conc;
        float sn = sinf(ang) * conc;
        r1[jj] = f2bf(f1[jj] * c - f2[jj] * sn);
        r2[jj] = f2bf(f2[jj] * c + f1[jj] * sn);
    }
    *(uint4v*)(qkv + base) = pack8(r1);
    *(uint4v*)(qkv + base + 32) = pack8(r2);
}

// ---------- GEMM: C[M,N] = A[M,K](bf16) @ B[N,K]^T + bias (+ resid) ----------
// Blocks: flattened id XCD-swizzled (T1, bijective since nwg%8==0 for all grids here):
//   each XCD gets a contiguous N-fast chunk -> A-panel L2 reuse within the XCD.
// GL path (BF16B + global_load_lds): double-buffered LDS, counted-vmcnt pipeline (T4):
//   prologue issues tiles 0,1; iter k waits vmcnt(L) (tile k landed, tile k+1 still in
//   flight), barrier, ds_read+MFMA from buf[k&1], lgkmcnt(0)+barrier, then issues tile
//   k+2 into buf[k&1]. Loads get ~2 full iterations to land; vmcnt never drains to 0
//   in the main loop. XOR chunk swizzle (p = c ^ (row&7)) -> 0 bank conflicts.
// Fallback: padded LDS + register prefetch (round-5 structure).
template <int BN, bool RESID, bool OUTF32, bool BF16B>
__global__ __launch_bounds__(256) void gemm_kernel(const ushort_t* __restrict__ A,
                                                   const void* __restrict__ B,
                                                   const float* __restrict__ bias,
                                                   const float* __restrict__ resid,
                                                   void* __restrict__ Cout, int M, int N, int K) {
    constexpr int BM = 128, BK = 64;
    constexpr bool GL = BF16B && (HAVE_GLDS != 0);
    constexpr int LDT = GL ? 64 : 72;
    constexpr int NBUF = GL ? 2 : 1;
    static_assert(BN == 160 || BN == 128 || BN == 96 || BN == 64, "");
    __shared__ __align__(16) ushort_t As[NBUF][BM * LDT];
    __shared__ __align__(16) ushort_t Bs[NBUF][BN * LDT];

    // XCD-aware chunked swizzle of the flattened block id (nwg % 8 == 0 for all grids)
    const int nbx = gridDim.x;
    int wg = blockIdx.y * nbx + blockIdx.x;
    {
        const int nwg = nbx * gridDim.y;
        const int cpx = nwg >> 3;
        wg = (wg & 7) * cpx + (wg >> 3);
    }
    const int m0 = (wg / nbx) * BM;
    const int n0 = (wg % nbx) * BN;
    const int tid = threadIdx.x;
    const int w = tid >> 6, lane = tid & 63;
    const int quad = lane >> 4, l16 = lane & 15;

    constexpr int WN = BN / 2;
    constexpr int NI = WN / 16;  // 5 / 4 / 3 / 2
    const int wm = (w >> 1) * 64;
    const int wn = (w & 1) * WN;

    float4v acc[4][NI];
#pragma unroll
    for (int i = 0; i < 4; ++i)
#pragma unroll
        for (int j = 0; j < NI; ++j) acc[i][j] = (float4v){0.f, 0.f, 0.f, 0.f};

    const int nk = K / BK;

#if HAVE_GLDS
    if constexpr (GL) {
        constexpr int NAI = BM / 32;  // glds issues per wave for A
        constexpr int NBI = BN / 32;  // glds issues per wave for B
        constexpr int L = NAI + NBI;  // loads per tile per wave
        const ushort_t* Bp = (const ushort_t*)B;
        const ushort_t* agp[NAI];
        const ushort_t* bgp[NBI];
        ushort_t* alp[2][NAI];
        ushort_t* blp[2][NBI];
#pragma unroll
        for (int i = 0; i < NAI; ++i) {
            int sb = (w * NAI + i) * 64;
            int s = sb + lane, r = s >> 3, p = s & 7, c = p ^ (r & 7);
            agp[i] = A + (size_t)(m0 + r) * K + c * 8;
            alp[0][i] = &As[0][sb * 8];
            alp[1][i] = &As[1][sb * 8];
        }
#pragma unroll
        for (int i = 0; i < NBI; ++i) {
            int sb = (w * NBI + i) * 64;
            int s = sb + lane, r = s >> 3, p = s & 7, c = p ^ (r & 7);
            bgp[i] = Bp + (size_t)(n0 + r) * K + c * 8;
            blp[0][i] = &Bs[0][sb * 8];
            blp[1][i] = &Bs[1][sb * 8];
        }
        // prologue: tile 0 -> buf0, tile 1 -> buf1 (2L loads in flight)
#pragma unroll
        for (int i = 0; i < NAI; ++i) glds16(agp[i], alp[0][i]);
#pragma unroll
        for (int i = 0; i < NBI; ++i) glds16(bgp[i], blp[0][i]);
        if (nk > 1) {
#pragma unroll
            for (int i = 0; i < NAI; ++i) glds16(agp[i] + BK, alp[1][i]);
#pragma unroll
            for (int i = 0; i < NBI; ++i) glds16(bgp[i] + BK, blp[1][i]);
        }

        for (int kt = 0; kt < nk; ++kt) {
            const int cur = kt & 1;
            // tile kt landed; tile kt+1 (L loads) may remain in flight
            if (kt + 1 < nk)
                asm volatile("s_waitcnt vmcnt(%0)" ::"n"(L) : "memory");
            else
                asm volatile("s_waitcnt vmcnt(0)" ::: "memory");
            __builtin_amdgcn_s_barrier();
            asm volatile("" ::: "memory");
            const ushort_t* Asb = As[cur];
            const ushort_t* Bsb = Bs[cur];
#pragma unroll
            for (int ks = 0; ks < 2; ++ks) {
                short8 af[4], bfr[NI];
#pragma unroll
                for (int mi = 0; mi < 4; ++mi) {
                    int row = wm + mi * 16 + l16;
                    af[mi] = *(const short8*)(Asb + row * LDT + ((ks * 4 + quad) ^ (row & 7)) * 8);
                }
#pragma unroll
                for (int ni = 0; ni < NI; ++ni) {
                    int row = wn + ni * 16 + l16;
                    bfr[ni] = *(const short8*)(Bsb + row * LDT + ((ks * 4 + quad) ^ (row & 7)) * 8);
                }
#pragma unroll
                for (int mi = 0; mi < 4; ++mi)
#pragma unroll
                    for (int ni = 0; ni < NI; ++ni)
                        acc[mi][ni] = mfma_bf16(af[mi], bfr[ni], acc[mi][ni]);
            }
            // my LDS reads of buf[cur] done -> after barrier it is free to overwrite
            asm volatile("s_waitcnt lgkmcnt(0)" ::: "memory");
            __builtin_amdgcn_s_barrier();
            asm volatile("" ::: "memory");
            if (kt + 2 < nk) {
                const int k0 = (kt + 2) * BK;
#pragma unroll
                for (int i = 0; i < NAI; ++i) glds16(agp[i] + k0, alp[cur][i]);
#pragma unroll
                for (int i = 0; i < NBI; ++i) glds16(bgp[i] + k0, blp[cur][i]);
            }
        }
    } else
#endif
    {
        // fallback: padded LDS + register prefetch (round-5 structure)
        constexpr int ACH = BM * BK / 8 / 256;
        constexpr int BCH = BN * BK / 8 / 256;
        uint4v areg[ACH], breg[BCH];
#pragma unroll
        for (int i = 0; i < ACH; ++i) {
            int c = tid + i * 256, r = c >> 3, col = c & 7;
            areg[i] = *(const uint4v*)(A + (size_t)(m0 + r) * K + col * 8);
        }
#pragma unroll
        for (int i = 0; i < BCH; ++i) {
            int c = tid + i * 256, r = c >> 3, col = c & 7;
            if constexpr (BF16B)
                breg[i] = *(const uint4v*)((const ushort_t*)B + (size_t)(n0 + r) * K + col * 8);
            else
                breg[i] = ld8f32_bf((const float*)B + (size_t)(n0 + r) * K + col * 8);
        }
        for (int kt = 0; kt < nk; ++kt) {
            __syncthreads();
#pragma unroll
            for (int i = 0; i < ACH; ++i) {
                int c = tid + i * 256, r = c >> 3, col = c & 7;
                *(uint4v*)(&As[0][r * LDT + col * 8]) = areg[i];
            }
#pragma unroll
            for (int i = 0; i < BCH; ++i) {
                int c = tid + i * 256, r = c >> 3, col = c & 7;
                *(uint4v*)(&Bs[0][r * LDT + col * 8]) = breg[i];
            }
            __syncthreads();
            if (kt + 1 < nk) {
                const int k0 = (kt + 1) * BK;
#pragma unroll
                for (int i = 0; i < ACH; ++i) {
                    int c = tid + i * 256, r = c >> 3, col = c & 7;
                    areg[i] = *(const uint4v*)(A + (size_t)(m0 + r) * K + k0 + col * 8);
                }
#pragma unroll
                for (int i = 0; i < BCH; ++i) {
                    int c = tid + i * 256, r = c >> 3, col = c & 7;
                    if constexpr (BF16B)
                        breg[i] = *(const uint4v*)((const ushort_t*)B + (size_t)(n0 + r) * K + k0 + col * 8);
                    else
                        breg[i] = ld8f32_bf((const float*)B + (size_t)(n0 + r) * K + k0 + col * 8);
                }
            }
#pragma unroll
            for (int ks = 0; ks < 2; ++ks) {
                short8 af[4], bfr[NI];
#pragma unroll
                for (int mi = 0; mi < 4; ++mi)
                    af[mi] = *(const short8*)(&As[0][(wm + mi * 16 + l16) * LDT + ks * 32 + quad * 8]);
#pragma unroll
                for (int ni = 0; ni < NI; ++ni)
                    bfr[ni] = *(const short8*)(&Bs[0][(wn + ni * 16 + l16) * LDT + ks * 32 + quad * 8]);
#pragma unroll
                for (int mi = 0; mi < 4; ++mi)
#pragma unroll
                    for (int ni = 0; ni < NI; ++ni)
                        acc[mi][ni] = mfma_bf16(af[mi], bfr[ni], acc[mi][ni]);
            }
        }
    }

    // epilogue: C/D layout col = lane&15, row = quad*4 + reg
#pragma unroll
    for (int ni = 0; ni < NI; ++ni) {
        int gc = n0 + wn + ni * 16 + l16;
        float bv = bias[gc];
#pragma unroll
        for (int mi = 0; mi < 4; ++mi) {
#pragma unroll
            for (int r = 0; r < 4; ++r) {
                int gr = m0 + wm + mi * 16 + quad * 4 + r;
                float vv = acc[mi][ni][r] + bv;
                if constexpr (RESID) vv += resid[(size_t)gr * N + gc];
                if constexpr (OUTF32) ((float*)Cout)[(size_t)gr * N + gc] = vv;
                else ((ushort_t*)Cout)[(size_t)gr * N + gc] = f2bf(vv);
            }
        }
    }
}

// ---------- MFMA attention: sliding window 128 + sink ----------
// Grid (qc 16, kvh*2+half 16, b 2) = 512 blocks, 2 blocks/CU (157.7KB LDS).
// Wave w handles head kvh*8 + half*4 + w, 4 query-tiles of 16.
__global__ __launch_bounds__(256, 2) void attn_mfma_kernel(const ushort_t* __restrict__ qkv,
                                                           const float* __restrict__ sinks,
                                                           ushort_t* __restrict__ attnbuf) {
    constexpr int LDK = 72, LDV = 200, LDP = 200;
    __shared__ __align__(16) ushort_t Ks[192 * LDK];
    __shared__ __align__(16) ushort_t Vt[64 * LDV];
    __shared__ __align__(16) ushort_t Pb[4][16 * LDP];

    const int qc = blockIdx.x, kvh = blockIdx.y >> 1, half = blockIdx.y & 1, b = blockIdx.z;
    const int tid = threadIdx.x;
    const int w = tid >> 6, lane = tid & 63;
    const int quad = lane >> 4, l16 = lane & 15;
    const int w0 = qc * 64 - 127;  // key position of LDS row 0

    for (int c = tid; c < 192 * 8; c += 256) {
        int row = c >> 3, col8 = c & 7;
        int pos = w0 + row;
        pos = pos < 0 ? 0 : (pos > 1023 ? 1023 : pos);
        size_t gk = ((size_t)(b * 1024 + pos)) * QKV_DIM + 4096 + kvh * 64 + col8 * 8;
        *(uint4v*)(Ks + row * LDK + col8 * 8) = *(const uint4v*)(qkv + gk);
        uint4v vv = *(const uint4v*)(qkv + gk + 512);
        ushort_t vs[8];
#pragma unroll
        for (int i = 0; i < 4; ++i) {
            vs[2 * i] = (ushort_t)(vv[i] & 0xffffu);
            vs[2 * i + 1] = (ushort_t)(vv[i] >> 16);
        }
#pragma unroll
        for (int j = 0; j < 8; ++j) Vt[(col8 * 8 + j) * LDV + row] = vs[j];
    }
    __syncthreads();

    // hoist V B-fragments: k = kt*32+quad*8+j, dim = nv*16+l16
    short8 Vf[6][4];
#pragma unroll
    for (int kt = 0; kt < 6; ++kt)
#pragma unroll
        for (int nv = 0; nv < 4; ++nv)
            Vf[kt][nv] = *(const short8*)(Vt + (nv * 16 + l16) * LDV + kt * 32 + quad * 8);

    ushort_t* Pw = Pb[w];
    const int h = kvh * 8 + half * 4 + w;
    const float sink_f = sinks[h];

    for (int qtile = 0; qtile < 4; ++qtile) {
        const int tokb = b * 1024 + qc * 64 + qtile * 16;

        short8 qf[2];
        {
            const ushort_t* qp = qkv + ((size_t)(tokb + l16)) * QKV_DIM + h * 64 + quad * 8;
            qf[0] = *(const short8*)qp;
            qf[1] = *(const short8*)(qp + 32);
        }

        float4v acc[12];
#pragma unroll
        for (int nt = 0; nt < 12; ++nt) acc[nt] = (float4v){0.f, 0.f, 0.f, 0.f};
#pragma unroll
        for (int nt = 0; nt < 12; ++nt) {
#pragma unroll
            for (int ks = 0; ks < 2; ++ks) {
                short8 kf = *(const short8*)(Ks + (nt * 16 + l16) * LDK + ks * 32 + quad * 8);
                acc[nt] = mfma_bf16(qf[ks], kf, acc[nt]);
            }
        }

        float linv[4];
#pragma unroll
        for (int r = 0; r < 4; ++r) {
            const int ql = qtile * 16 + quad * 4 + r;
            float e[12];
            float mx = -1e30f;
#pragma unroll
            for (int nt = 0; nt < 12; ++nt) {
                int row_k = nt * 16 + l16;
                bool valid = (row_k >= ql) && (row_k <= ql + 127) && (w0 + row_k >= 0);
                float s = valid ? acc[nt][r] * SM_SCALE : -1e30f;
                e[nt] = s;
                mx = fmaxf(mx, s);
            }
#pragma unroll
            for (int o = 1; o < 16; o <<= 1) mx = fmaxf(mx, __shfl_xor(mx, o));
            float M = fmaxf(mx, sink_f);
            float ls = 0.f;
#pragma unroll
            for (int nt = 0; nt < 12; ++nt) {
                float ev = (e[nt] > -1e29f) ? __expf(e[nt] - M) : 0.f;
                e[nt] = ev;
                ls += ev;
            }
#pragma unroll
            for (int o = 1; o < 16; o <<= 1) ls += __shfl_xor(ls, o);
            linv[r] = 1.f / (ls + __expf(sink_f - M));
#pragma unroll
            for (int nt = 0; nt < 12; ++nt)
                Pw[(quad * 4 + r) * LDP + nt * 16 + l16] = f2bf(e[nt]);
        }

        float4v accO[4];
#pragma unroll
        for (int nv = 0; nv < 4; ++nv) accO[nv] = (float4v){0.f, 0.f, 0.f, 0.f};
#pragma unroll
        for (int kt = 0; kt < 6; ++kt) {
            short8 pf = *(const short8*)(Pw + l16 * LDP + kt * 32 + quad * 8);
#pragma unroll
            for (int nv = 0; nv < 4; ++nv) accO[nv] = mfma_bf16(pf, Vf[kt][nv], accO[nv]);
        }

#pragma unroll
        for (int r = 0; r < 4; ++r) {
            size_t ob = ((size_t)(tokb + quad * 4 + r)) * ATTN_DIM + h * 64 + l16;
#pragma unroll
            for (int nv = 0; nv < 4; ++nv)
                attnbuf[ob + nv * 16] = f2bf(accO[nv][r] * linv[r]);
        }
    }
}

// ---------- launch ----------
extern "C" void kernel_launch(void* const* d_in, const int* in_sizes, int n_in,
                              void* d_out, int out_size, void* d_ws, size_t ws_size,
                              hipStream_t stream) {
    const float* x = (const float*)d_in[0];
    const float* norm_w = (const float*)d_in[1];
    const float* qkv_w = (const float*)d_in[2];
    const float* qkv_b = (const float*)d_in[3];
    const float* out_w = (const float*)d_in[4];
    const float* out_b = (const float*)d_in[5];
    const float* sinks = (const float*)d_in[6];
    float* outp = (float*)d_out;
    char* ws = (char*)d_ws;

    if (ws_size >= 86000000ull) {
        // qkvbuf 21MB | {qkv_w_bf 29.5MB -> attnbuf 16.8MB} | Tbuf 11.8MB | out_w_bf 23.6MB
        ushort_t* qkvbuf = (ushort_t*)ws;
        ushort_t* qkv_w_bf = (ushort_t*)(ws + 20971520);
        ushort_t* attnbuf = (ushort_t*)(ws + 20971520);  // reuse after gemm1 consumed qkv_w_bf
        ushort_t* Tbuf = (ushort_t*)(ws + 50462720);
        ushort_t* out_w_bf = (ushort_t*)(ws + 62259200);

        f32_to_bf16_dual_kernel<<<12960, 256, 0, stream>>>(qkv_w, qkv_w_bf, 1843200,
                                                           out_w, out_w_bf, 1474560);
        rmsnorm_kernel<<<NTOK, 256, 0, stream>>>(x, norm_w, Tbuf);
        gemm_kernel<160, false, false, true><<<dim3(32, 16), 256, 0, stream>>>(
            Tbuf, qkv_w_bf, qkv_b, nullptr, qkvbuf, NTOK, QKV_DIM, HIDDEN);
        rope_apply_kernel<<<2304, 256, 0, stream>>>(qkvbuf);
        attn_mfma_kernel<<<dim3(16, 16, 2), 256, 0, stream>>>(qkvbuf, sinks, attnbuf);
        gemm_kernel<96, true, true, true><<<dim3(30, 16), 256, 0, stream>>>(
            attnbuf, out_w_bf, out_b, x, outp, NTOK, HIDDEN, ATTN_DIM);
    } else {
        // fallback: fp32 B loads (register staging), Tbuf in d_out
        ushort_t* qkvbuf = (ushort_t*)ws;
        ushort_t* attnbuf = (ushort_t*)(ws + 20971520);
        ushort_t* Tbuf = (ushort_t*)d_out;

        rmsnorm_kernel<<<NTOK, 256, 0, stream>>>(x, norm_w, Tbuf);
        gemm_kernel<128, false, false, false><<<dim3(40, 16), 256, 0, stream>>>(
            Tbuf, qkv_w, qkv_b, nullptr, qkvbuf, NTOK, QKV_DIM, HIDDEN);
        rope_apply_kernel<<<2304, 256, 0, stream>>>(qkvbuf);
        attn_mfma_kernel<<<dim3(16, 16, 2), 256, 0, stream>>>(qkvbuf, sinks, attnbuf);
        gemm_kernel<96, true, true, false><<<dim3(30, 16), 256, 0, stream>>>(
            attnbuf, out_w, out_b, x, outp, NTOK, HIDDEN, ATTN_DIM);
    }
}

// Round 3
// 317.091 us; speedup vs baseline: 1.0713x; 1.0713x over previous
//
#include <hip/hip_runtime.h>

typedef unsigned short ushort_t;
typedef __attribute__((ext_vector_type(8))) short short8;
typedef __attribute__((ext_vector_type(8))) __bf16 bf16x8;
typedef __attribute__((ext_vector_type(4))) float float4v;
typedef __attribute__((ext_vector_type(4))) unsigned int uint4v;

// ---------- bf16 helpers ----------
__device__ __forceinline__ float bf2f(ushort_t u) {
    unsigned int v = ((unsigned int)u) << 16;
    return __builtin_bit_cast(float, v);
}
__device__ __forceinline__ ushort_t f2bf(float f) {
    unsigned int u = __builtin_bit_cast(unsigned int, f);
    unsigned int lsb = (u >> 16) & 1u;
    u += 0x7fffu + lsb;  // round-to-nearest-even
    return (ushort_t)(u >> 16);
}
__device__ __forceinline__ uint4v pack8(const ushort_t* r) {
    uint4v u;
#pragma unroll
    for (int i = 0; i < 4; ++i)
        u[i] = (unsigned int)r[2 * i] | ((unsigned int)r[2 * i + 1] << 16);
    return u;
}
__device__ __forceinline__ void unpack8(uint4v u, float* f) {
#pragma unroll
    for (int i = 0; i < 4; ++i) {
        unsigned int x = u[i];
        f[2 * i] = __builtin_bit_cast(float, x << 16);
        f[2 * i + 1] = __builtin_bit_cast(float, x & 0xffff0000u);
    }
}
__device__ __forceinline__ uint4v ld8f32_bf(const float* p) {
    float4v a = *(const float4v*)p;
    float4v b = *(const float4v*)(p + 4);
    ushort_t r[8];
#pragma unroll
    for (int j = 0; j < 4; ++j) { r[j] = f2bf(a[j]); r[4 + j] = f2bf(b[j]); }
    return pack8(r);
}

// ---------- async global->LDS (16B per lane, dest = uniform base + lane*16) ----------
#if __has_builtin(__builtin_amdgcn_global_load_lds)
#define HAVE_GLDS 1
__device__ __forceinline__ void glds16(const ushort_t* gp, ushort_t* lp) {
    __builtin_amdgcn_global_load_lds((const __attribute__((address_space(1))) void*)gp,
                                     (__attribute__((address_space(3))) void*)lp, 16, 0, 0);
}
#else
#define HAVE_GLDS 0
#endif

// ---------- MFMA hedge ----------
template <typename V>
__device__ __forceinline__ auto mfma_sel(V a, V b, float4v c, int)
    -> decltype(__builtin_amdgcn_mfma_f32_16x16x32_bf16(a, b, c, 0, 0, 0)) {
    return __builtin_amdgcn_mfma_f32_16x16x32_bf16(a, b, c, 0, 0, 0);
}
template <typename V>
__device__ __forceinline__ float4v mfma_sel(V a, V b, float4v c, long) {
    return __builtin_amdgcn_mfma_f32_16x16x32_bf16(__builtin_bit_cast(bf16x8, a),
                                                   __builtin_bit_cast(bf16x8, b), c, 0, 0, 0);
}
__device__ __forceinline__ float4v mfma_bf16(short8 a, short8 b, float4v c) {
    return mfma_sel(a, b, c, 0);
}

__device__ __forceinline__ float wave_sum(float v) {
#pragma unroll
    for (int o = 32; o; o >>= 1) v += __shfl_xor(v, o);
    return v;
}

// ---------- constants ----------
#define HIDDEN 2880
#define NTOK 2048
#define QKV_DIM 5120
#define ATTN_DIM 4096
#define SM_SCALE 0.125f

// ---------- fp32 -> bf16 bulk convert (dual source; 2nd output zero-padded to nb8_pad) ----------
__global__ __launch_bounds__(256) void f32_to_bf16_dual_kernel(const float* __restrict__ a,
                                                               ushort_t* __restrict__ ao, int na8,
                                                               const float* __restrict__ b,
                                                               ushort_t* __restrict__ bo,
                                                               int nb8_real, int nb8_pad) {
    int idx = blockIdx.x * 256 + threadIdx.x;
    if (idx < na8) {
        *(uint4v*)(ao + (size_t)idx * 8) = ld8f32_bf(a + (size_t)idx * 8);
    } else {
        int j = idx - na8;
        if (j < nb8_pad) {
            uint4v z = {0u, 0u, 0u, 0u};
            *(uint4v*)(bo + (size_t)j * 8) = (j < nb8_real) ? ld8f32_bf(b + (size_t)j * 8) : z;
        }
    }
}

// ---------- RMSNorm: fp32 x -> bf16 normed ----------
__global__ __launch_bounds__(256) void rmsnorm_kernel(const float* __restrict__ x,
                                                      const float* __restrict__ wgt,
                                                      ushort_t* __restrict__ out) {
    const int tok = blockIdx.x, tid = threadIdx.x;
    const float* xr = x + (size_t)tok * HIDDEN;
    float v[16];
    float ss = 0.f;
#pragma unroll
    for (int i = 0; i < 2; ++i) {
        int c = tid + i * 256;
        if (c < 360) {
            float4v a = *(const float4v*)(xr + c * 8);
            float4v b = *(const float4v*)(xr + c * 8 + 4);
#pragma unroll
            for (int j = 0; j < 4; ++j) { v[i * 8 + j] = a[j]; v[i * 8 + 4 + j] = b[j]; }
#pragma unroll
            for (int j = 0; j < 8; ++j) ss += v[i * 8 + j] * v[i * 8 + j];
        }
    }
    ss = wave_sum(ss);
    __shared__ float red[4];
    if ((tid & 63) == 0) red[tid >> 6] = ss;
    __syncthreads();
    float scale = rsqrtf((red[0] + red[1] + red[2] + red[3]) * (1.f / 2880.f) + 1e-5f);
#pragma unroll
    for (int i = 0; i < 2; ++i) {
        int c = tid + i * 256;
        if (c < 360) {
            float4v wa = *(const float4v*)(wgt + c * 8);
            float4v wb = *(const float4v*)(wgt + c * 8 + 4);
            ushort_t r[8];
#pragma unroll
            for (int j = 0; j < 4; ++j) {
                r[j] = f2bf(v[i * 8 + j] * scale * wa[j]);
                r[4 + j] = f2bf(v[i * 8 + 4 + j] * scale * wb[j]);
            }
            *(uint4v*)(out + (size_t)tok * HIDDEN + c * 8) = pack8(r);
        }
    }
}

// ---------- RoPE apply, YaRN cos/sin on the fly ----------
__global__ __launch_bounds__(256) void rope_apply_kernel(ushort_t* __restrict__ qkv) {
    int idx = blockIdx.x * 256 + threadIdx.x;  // 2048 * 72 * 4
    int tok = idx / 288;
    int rem = idx - tok * 288;
    int h = rem >> 2, dg = rem & 3;
    int s = tok & 1023;
    size_t base = (size_t)tok * QKV_DIM + (h < 64 ? h * 64 : 4096 + (h - 64) * 64) + dg * 8;
    uint4v u1 = *(const uint4v*)(qkv + base);
    uint4v u2 = *(const uint4v*)(qkv + base + 32);
    float f1[8], f2[8];
    unpack8(u1, f1);
    unpack8(u2, f2);
    const float step = (float)(11.918390573078392 / 32.0);
    const float conc = (float)(1.3465735902799727);
    const float low = (float)(8.092890725542669);
    const float invden = (float)(1.0 / 9.305804387286162);
    ushort_t r1[8], r2[8];
#pragma unroll
    for (int jj = 0; jj < 8; ++jj) {
        int j = dg * 8 + jj;
        float invf = __expf(-(float)j * step);
        float ramp = ((float)j - low) * invden;
        float mask = 1.f - fminf(fmaxf(ramp, 0.f), 1.f);
        float inv_freq = invf * ((1.f - mask) * 0.03125f + mask);
        float ang = (float)s * inv_freq;
        float c = cosf(ang) * conc;
        float sn = sinf(ang) * conc;
        r1[jj] = f2bf(f1[jj] * c - f2[jj] * sn);
        r2[jj] = f2bf(f2[jj] * c + f1[jj] * sn);
    }
    *(uint4v*)(qkv + base) = pack8(r1);
    *(uint4v*)(qkv + base + 32) = pack8(r2);
}

// ---------- GEMM: C[M,N] = A[M,K](bf16) @ B[N,K]^T + bias (+ resid) ----------
// Blocks: flattened id XCD-swizzled (T1, bijective since nwg%8==0 for all grids here):
//   each XCD gets a contiguous N-fast chunk -> A-panel L2 reuse within the XCD.
// GL path (BF16B + global_load_lds): double-buffered LDS, ONE barrier per K-iter
//   (round-1 proven schedule: issue async tile k+1 -> buf^1, compute tile k, barrier;
//   the compiler's vmcnt drain at the barrier lands after the compute phase).
//   XOR chunk swizzle (p = c ^ (row&7)) -> 0 bank conflicts.
// NMASK: B is row-padded past N (zeros); epilogue skips bias read + stores for gc>=N.
// Fallback: padded LDS + register prefetch (round-5 structure).
template <int BN, bool RESID, bool OUTF32, bool BF16B, bool NMASK = false>
__global__ __launch_bounds__(256) void gemm_kernel(const ushort_t* __restrict__ A,
                                                   const void* __restrict__ B,
                                                   const float* __restrict__ bias,
                                                   const float* __restrict__ resid,
                                                   void* __restrict__ Cout, int M, int N, int K) {
    constexpr int BM = 128, BK = 64;
    constexpr bool GL = BF16B && (HAVE_GLDS != 0);
    constexpr int LDT = GL ? 64 : 72;
    constexpr int NBUF = GL ? 2 : 1;
    static_assert(BN == 160 || BN == 128 || BN == 96 || BN == 64, "");
    __shared__ __align__(16) ushort_t As[NBUF][BM * LDT];
    __shared__ __align__(16) ushort_t Bs[NBUF][BN * LDT];

    // XCD-aware chunked swizzle of the flattened block id (nwg % 8 == 0 for all grids)
    const int nbx = gridDim.x;
    int wg = blockIdx.y * nbx + blockIdx.x;
    {
        const int nwg = nbx * gridDim.y;
        const int cpx = nwg >> 3;
        wg = (wg & 7) * cpx + (wg >> 3);
    }
    const int m0 = (wg / nbx) * BM;
    const int n0 = (wg % nbx) * BN;
    const int tid = threadIdx.x;
    const int w = tid >> 6, lane = tid & 63;
    const int quad = lane >> 4, l16 = lane & 15;

    constexpr int WN = BN / 2;
    constexpr int NI = WN / 16;  // 5 / 4 / 3 / 2
    const int wm = (w >> 1) * 64;
    const int wn = (w & 1) * WN;

    float4v acc[4][NI];
#pragma unroll
    for (int i = 0; i < 4; ++i)
#pragma unroll
        for (int j = 0; j < NI; ++j) acc[i][j] = (float4v){0.f, 0.f, 0.f, 0.f};

    const int nk = K / BK;

#if HAVE_GLDS
    if constexpr (GL) {
        constexpr int NAI = BM / 32;  // glds issues per wave for A
        constexpr int NBI = BN / 32;  // glds issues per wave for B
        const ushort_t* Bp = (const ushort_t*)B;
        const ushort_t* agp[NAI];
        const ushort_t* bgp[NBI];
        ushort_t* alp[2][NAI];
        ushort_t* blp[2][NBI];
#pragma unroll
        for (int i = 0; i < NAI; ++i) {
            int sb = (w * NAI + i) * 64;
            int s = sb + lane, r = s >> 3, p = s & 7, c = p ^ (r & 7);
            agp[i] = A + (size_t)(m0 + r) * K + c * 8;
            alp[0][i] = &As[0][sb * 8];
            alp[1][i] = &As[1][sb * 8];
        }
#pragma unroll
        for (int i = 0; i < NBI; ++i) {
            int sb = (w * NBI + i) * 64;
            int s = sb + lane, r = s >> 3, p = s & 7, c = p ^ (r & 7);
            bgp[i] = Bp + (size_t)(n0 + r) * K + c * 8;
            blp[0][i] = &Bs[0][sb * 8];
            blp[1][i] = &Bs[1][sb * 8];
        }
        // prologue: tile 0 -> buf 0
#pragma unroll
        for (int i = 0; i < NAI; ++i) glds16(agp[i], alp[0][i]);
#pragma unroll
        for (int i = 0; i < NBI; ++i) glds16(bgp[i], blp[0][i]);
        __syncthreads();

        for (int kt = 0; kt < nk; ++kt) {
            const int cur = kt & 1;
            if (kt + 1 < nk) {
                const int k0 = (kt + 1) * BK;
#pragma unroll
                for (int i = 0; i < NAI; ++i) glds16(agp[i] + k0, alp[cur ^ 1][i]);
#pragma unroll
                for (int i = 0; i < NBI; ++i) glds16(bgp[i] + k0, blp[cur ^ 1][i]);
            }
            const ushort_t* Asb = As[cur];
            const ushort_t* Bsb = Bs[cur];
#pragma unroll
            for (int ks = 0; ks < 2; ++ks) {
                short8 af[4], bfr[NI];
#pragma unroll
                for (int mi = 0; mi < 4; ++mi) {
                    int row = wm + mi * 16 + l16;
                    af[mi] = *(const short8*)(Asb + row * LDT + ((ks * 4 + quad) ^ (row & 7)) * 8);
                }
#pragma unroll
                for (int ni = 0; ni < NI; ++ni) {
                    int row = wn + ni * 16 + l16;
                    bfr[ni] = *(const short8*)(Bsb + row * LDT + ((ks * 4 + quad) ^ (row & 7)) * 8);
                }
#pragma unroll
                for (int mi = 0; mi < 4; ++mi)
#pragma unroll
                    for (int ni = 0; ni < NI; ++ni)
                        acc[mi][ni] = mfma_bf16(af[mi], bfr[ni], acc[mi][ni]);
            }
            __syncthreads();
        }
    } else
#endif
    {
        // fallback: padded LDS + register prefetch (round-5 structure)
        constexpr int ACH = BM * BK / 8 / 256;
        constexpr int BCH = BN * BK / 8 / 256;
        uint4v areg[ACH], breg[BCH];
#pragma unroll
        for (int i = 0; i < ACH; ++i) {
            int c = tid + i * 256, r = c >> 3, col = c & 7;
            areg[i] = *(const uint4v*)(A + (size_t)(m0 + r) * K + col * 8);
        }
#pragma unroll
        for (int i = 0; i < BCH; ++i) {
            int c = tid + i * 256, r = c >> 3, col = c & 7;
            if constexpr (BF16B)
                breg[i] = *(const uint4v*)((const ushort_t*)B + (size_t)(n0 + r) * K + col * 8);
            else
                breg[i] = ld8f32_bf((const float*)B + (size_t)(n0 + r) * K + col * 8);
        }
        for (int kt = 0; kt < nk; ++kt) {
            __syncthreads();
#pragma unroll
            for (int i = 0; i < ACH; ++i) {
                int c = tid + i * 256, r = c >> 3, col = c & 7;
                *(uint4v*)(&As[0][r * LDT + col * 8]) = areg[i];
            }
#pragma unroll
            for (int i = 0; i < BCH; ++i) {
                int c = tid + i * 256, r = c >> 3, col = c & 7;
                *(uint4v*)(&Bs[0][r * LDT + col * 8]) = breg[i];
            }
            __syncthreads();
            if (kt + 1 < nk) {
                const int k0 = (kt + 1) * BK;
#pragma unroll
                for (int i = 0; i < ACH; ++i) {
                    int c = tid + i * 256, r = c >> 3, col = c & 7;
                    areg[i] = *(const uint4v*)(A + (size_t)(m0 + r) * K + k0 + col * 8);
                }
#pragma unroll
                for (int i = 0; i < BCH; ++i) {
                    int c = tid + i * 256, r = c >> 3, col = c & 7;
                    if constexpr (BF16B)
                        breg[i] = *(const uint4v*)((const ushort_t*)B + (size_t)(n0 + r) * K + k0 + col * 8);
                    else
                        breg[i] = ld8f32_bf((const float*)B + (size_t)(n0 + r) * K + k0 + col * 8);
                }
            }
#pragma unroll
            for (int ks = 0; ks < 2; ++ks) {
                short8 af[4], bfr[NI];
#pragma unroll
                for (int mi = 0; mi < 4; ++mi)
                    af[mi] = *(const short8*)(&As[0][(wm + mi * 16 + l16) * LDT + ks * 32 + quad * 8]);
#pragma unroll
                for (int ni = 0; ni < NI; ++ni)
                    bfr[ni] = *(const short8*)(&Bs[0][(wn + ni * 16 + l16) * LDT + ks * 32 + quad * 8]);
#pragma unroll
                for (int mi = 0; mi < 4; ++mi)
#pragma unroll
                    for (int ni = 0; ni < NI; ++ni)
                        acc[mi][ni] = mfma_bf16(af[mi], bfr[ni], acc[mi][ni]);
            }
        }
    }

    // epilogue: C/D layout col = lane&15, row = quad*4 + reg
#pragma unroll
    for (int ni = 0; ni < NI; ++ni) {
        int gc = n0 + wn + ni * 16 + l16;
        if (NMASK && gc >= N) continue;  // padded-N columns: no bias, no store
        float bv = bias[gc];
#pragma unroll
        for (int mi = 0; mi < 4; ++mi) {
#pragma unroll
            for (int r = 0; r < 4; ++r) {
                int gr = m0 + wm + mi * 16 + quad * 4 + r;
                float vv = acc[mi][ni][r] + bv;
                if constexpr (RESID) vv += resid[(size_t)gr * N + gc];
                if constexpr (OUTF32) ((float*)Cout)[(size_t)gr * N + gc] = vv;
                else ((ushort_t*)Cout)[(size_t)gr * N + gc] = f2bf(vv);
            }
        }
    }
}

// ---------- MFMA attention: sliding window 128 + sink ----------
// Grid (qc 16, kvh*2+half 16, b 2) = 512 blocks, 2 blocks/CU (157.7KB LDS).
// Wave w handles head kvh*8 + half*4 + w, 4 query-tiles of 16.
__global__ __launch_bounds__(256, 2) void attn_mfma_kernel(const ushort_t* __restrict__ qkv,
                                                           const float* __restrict__ sinks,
                                                           ushort_t* __restrict__ attnbuf) {
    constexpr int LDK = 72, LDV = 200, LDP = 200;
    __shared__ __align__(16) ushort_t Ks[192 * LDK];
    __shared__ __align__(16) ushort_t Vt[64 * LDV];
    __shared__ __align__(16) ushort_t Pb[4][16 * LDP];

    const int qc = blockIdx.x, kvh = blockIdx.y >> 1, half = blockIdx.y & 1, b = blockIdx.z;
    const int tid = threadIdx.x;
    const int w = tid >> 6, lane = tid & 63;
    const int quad = lane >> 4, l16 = lane & 15;
    const int w0 = qc * 64 - 127;  // key position of LDS row 0

    for (int c = tid; c < 192 * 8; c += 256) {
        int row = c >> 3, col8 = c & 7;
        int pos = w0 + row;
        pos = pos < 0 ? 0 : (pos > 1023 ? 1023 : pos);
        size_t gk = ((size_t)(b * 1024 + pos)) * QKV_DIM + 4096 + kvh * 64 + col8 * 8;
        *(uint4v*)(Ks + row * LDK + col8 * 8) = *(const uint4v*)(qkv + gk);
        uint4v vv = *(const uint4v*)(qkv + gk + 512);
        ushort_t vs[8];
#pragma unroll
        for (int i = 0; i < 4; ++i) {
            vs[2 * i] = (ushort_t)(vv[i] & 0xffffu);
            vs[2 * i + 1] = (ushort_t)(vv[i] >> 16);
        }
#pragma unroll
        for (int j = 0; j < 8; ++j) Vt[(col8 * 8 + j) * LDV + row] = vs[j];
    }
    __syncthreads();

    // hoist V B-fragments: k = kt*32+quad*8+j, dim = nv*16+l16
    short8 Vf[6][4];
#pragma unroll
    for (int kt = 0; kt < 6; ++kt)
#pragma unroll
        for (int nv = 0; nv < 4; ++nv)
            Vf[kt][nv] = *(const short8*)(Vt + (nv * 16 + l16) * LDV + kt * 32 + quad * 8);

    ushort_t* Pw = Pb[w];
    const int h = kvh * 8 + half * 4 + w;
    const float sink_f = sinks[h];

    for (int qtile = 0; qtile < 4; ++qtile) {
        const int tokb = b * 1024 + qc * 64 + qtile * 16;

        short8 qf[2];
        {
            const ushort_t* qp = qkv + ((size_t)(tokb + l16)) * QKV_DIM + h * 64 + quad * 8;
            qf[0] = *(const short8*)qp;
            qf[1] = *(const short8*)(qp + 32);
        }

        float4v acc[12];
#pragma unroll
        for (int nt = 0; nt < 12; ++nt) acc[nt] = (float4v){0.f, 0.f, 0.f, 0.f};
#pragma unroll
        for (int nt = 0; nt < 12; ++nt) {
#pragma unroll
            for (int ks = 0; ks < 2; ++ks) {
                short8 kf = *(const short8*)(Ks + (nt * 16 + l16) * LDK + ks * 32 + quad * 8);
                acc[nt] = mfma_bf16(qf[ks], kf, acc[nt]);
            }
        }

        float linv[4];
#pragma unroll
        for (int r = 0; r < 4; ++r) {
            const int ql = qtile * 16 + quad * 4 + r;
            float e[12];
            float mx = -1e30f;
#pragma unroll
            for (int nt = 0; nt < 12; ++nt) {
                int row_k = nt * 16 + l16;
                bool valid = (row_k >= ql) && (row_k <= ql + 127) && (w0 + row_k >= 0);
                float s = valid ? acc[nt][r] * SM_SCALE : -1e30f;
                e[nt] = s;
                mx = fmaxf(mx, s);
            }
#pragma unroll
            for (int o = 1; o < 16; o <<= 1) mx = fmaxf(mx, __shfl_xor(mx, o));
            float M = fmaxf(mx, sink_f);
            float ls = 0.f;
#pragma unroll
            for (int nt = 0; nt < 12; ++nt) {
                float ev = (e[nt] > -1e29f) ? __expf(e[nt] - M) : 0.f;
                e[nt] = ev;
                ls += ev;
            }
#pragma unroll
            for (int o = 1; o < 16; o <<= 1) ls += __shfl_xor(ls, o);
            linv[r] = 1.f / (ls + __expf(sink_f - M));
#pragma unroll
            for (int nt = 0; nt < 12; ++nt)
                Pw[(quad * 4 + r) * LDP + nt * 16 + l16] = f2bf(e[nt]);
        }

        float4v accO[4];
#pragma unroll
        for (int nv = 0; nv < 4; ++nv) accO[nv] = (float4v){0.f, 0.f, 0.f, 0.f};
#pragma unroll
        for (int kt = 0; kt < 6; ++kt) {
            short8 pf = *(const short8*)(Pw + l16 * LDP + kt * 32 + quad * 8);
#pragma unroll
            for (int nv = 0; nv < 4; ++nv) accO[nv] = mfma_bf16(pf, Vf[kt][nv], accO[nv]);
        }

#pragma unroll
        for (int r = 0; r < 4; ++r) {
            size_t ob = ((size_t)(tokb + quad * 4 + r)) * ATTN_DIM + h * 64 + l16;
#pragma unroll
            for (int nv = 0; nv < 4; ++nv)
                attnbuf[ob + nv * 16] = f2bf(accO[nv][r] * linv[r]);
        }
    }
}

// ---------- launch ----------
extern "C" void kernel_launch(void* const* d_in, const int* in_sizes, int n_in,
                              void* d_out, int out_size, void* d_ws, size_t ws_size,
                              hipStream_t stream) {
    const float* x = (const float*)d_in[0];
    const float* norm_w = (const float*)d_in[1];
    const float* qkv_w = (const float*)d_in[2];
    const float* qkv_b = (const float*)d_in[3];
    const float* out_w = (const float*)d_in[4];
    const float* out_b = (const float*)d_in[5];
    const float* sinks = (const float*)d_in[6];
    float* outp = (float*)d_out;
    char* ws = (char*)d_ws;

    if (ws_size >= 86000000ull) {
        // ws: qkvbuf 21MB | {qkv_w_bf 29.5MB -> attnbuf 16.8MB} | out_w_bf padded 25.2MB
        // Tbuf lives in d_out (dead before GEMM2 overwrites d_out).
        ushort_t* qkvbuf = (ushort_t*)ws;
        ushort_t* qkv_w_bf = (ushort_t*)(ws + 20971520);
        ushort_t* attnbuf = (ushort_t*)(ws + 20971520);  // reuse after gemm1 consumed qkv_w_bf
        ushort_t* out_w_bf = (ushort_t*)(ws + 50462720); // 3072x4096 bf16 (rows 2880+ zeroed)
        ushort_t* Tbuf = (ushort_t*)d_out;

        // qkv_w: 5120*2880/8 = 1843200 chunks; out_w: real 2880*4096/8 = 1474560,
        // padded 3072*4096/8 = 1572864. grid = (1843200+1572864)/256 = 13344.
        f32_to_bf16_dual_kernel<<<13344, 256, 0, stream>>>(qkv_w, qkv_w_bf, 1843200,
                                                           out_w, out_w_bf, 1474560, 1572864);
        rmsnorm_kernel<<<NTOK, 256, 0, stream>>>(x, norm_w, Tbuf);
        gemm_kernel<160, false, false, true><<<dim3(32, 16), 256, 0, stream>>>(
            Tbuf, qkv_w_bf, qkv_b, nullptr, qkvbuf, NTOK, QKV_DIM, HIDDEN);
        rope_apply_kernel<<<2304, 256, 0, stream>>>(qkvbuf);
        attn_mfma_kernel<<<dim3(16, 16, 2), 256, 0, stream>>>(qkvbuf, sinks, attnbuf);
        // N padded 2880->3072: BN=128, grid (24,16)=384 blocks, masked epilogue
        gemm_kernel<128, true, true, true, true><<<dim3(24, 16), 256, 0, stream>>>(
            attnbuf, out_w_bf, out_b, x, outp, NTOK, HIDDEN, ATTN_DIM);
    } else {
        // fallback: fp32 B loads (register staging), Tbuf in d_out
        ushort_t* qkvbuf = (ushort_t*)ws;
        ushort_t* attnbuf = (ushort_t*)(ws + 20971520);
        ushort_t* Tbuf = (ushort_t*)d_out;

        rmsnorm_kernel<<<NTOK, 256, 0, stream>>>(x, norm_w, Tbuf);
        gemm_kernel<128, false, false, false><<<dim3(40, 16), 256, 0, stream>>>(
            Tbuf, qkv_w, qkv_b, nullptr, qkvbuf, NTOK, QKV_DIM, HIDDEN);
        rope_apply_kernel<<<2304, 256, 0, stream>>>(qkvbuf);
        attn_mfma_kernel<<<dim3(16, 16, 2), 256, 0, stream>>>(qkvbuf, sinks, attnbuf);
        gemm_kernel<96, true, true, false><<<dim3(30, 16), 256, 0, stream>>>(
            attnbuf, out_w, out_b, x, outp, NTOK, HIDDEN, ATTN_DIM);
    }
}

// Round 4
// 316.776 us; speedup vs baseline: 1.0724x; 1.0010x over previous
//
#include <hip/hip_runtime.h>

typedef unsigned short ushort_t;
typedef __attribute__((ext_vector_type(8))) short short8;
typedef __attribute__((ext_vector_type(8))) __bf16 bf16x8;
typedef __attribute__((ext_vector_type(4))) float float4v;
typedef __attribute__((ext_vector_type(4))) unsigned int uint4v;

// ---------- bf16 helpers ----------
__device__ __forceinline__ float bf2f(ushort_t u) {
    unsigned int v = ((unsigned int)u) << 16;
    return __builtin_bit_cast(float, v);
}
__device__ __forceinline__ ushort_t f2bf(float f) {
    unsigned int u = __builtin_bit_cast(unsigned int, f);
    unsigned int lsb = (u >> 16) & 1u;
    u += 0x7fffu + lsb;  // round-to-nearest-even
    return (ushort_t)(u >> 16);
}
__device__ __forceinline__ uint4v pack8(const ushort_t* r) {
    uint4v u;
#pragma unroll
    for (int i = 0; i < 4; ++i)
        u[i] = (unsigned int)r[2 * i] | ((unsigned int)r[2 * i + 1] << 16);
    return u;
}
__device__ __forceinline__ void unpack8(uint4v u, float* f) {
#pragma unroll
    for (int i = 0; i < 4; ++i) {
        unsigned int x = u[i];
        f[2 * i] = __builtin_bit_cast(float, x << 16);
        f[2 * i + 1] = __builtin_bit_cast(float, x & 0xffff0000u);
    }
}
__device__ __forceinline__ uint4v ld8f32_bf(const float* p) {
    float4v a = *(const float4v*)p;
    float4v b = *(const float4v*)(p + 4);
    ushort_t r[8];
#pragma unroll
    for (int j = 0; j < 4; ++j) { r[j] = f2bf(a[j]); r[4 + j] = f2bf(b[j]); }
    return pack8(r);
}

// ---------- async global->LDS (16B per lane, dest = uniform base + lane*16) ----------
#if __has_builtin(__builtin_amdgcn_global_load_lds)
#define HAVE_GLDS 1
__device__ __forceinline__ void glds16(const ushort_t* gp, ushort_t* lp) {
    __builtin_amdgcn_global_load_lds((const __attribute__((address_space(1))) void*)gp,
                                     (__attribute__((address_space(3))) void*)lp, 16, 0, 0);
}
#else
#define HAVE_GLDS 0
#endif

// ---------- MFMA hedge ----------
template <typename V>
__device__ __forceinline__ auto mfma_sel(V a, V b, float4v c, int)
    -> decltype(__builtin_amdgcn_mfma_f32_16x16x32_bf16(a, b, c, 0, 0, 0)) {
    return __builtin_amdgcn_mfma_f32_16x16x32_bf16(a, b, c, 0, 0, 0);
}
template <typename V>
__device__ __forceinline__ float4v mfma_sel(V a, V b, float4v c, long) {
    return __builtin_amdgcn_mfma_f32_16x16x32_bf16(__builtin_bit_cast(bf16x8, a),
                                                   __builtin_bit_cast(bf16x8, b), c, 0, 0, 0);
}
__device__ __forceinline__ float4v mfma_bf16(short8 a, short8 b, float4v c) {
    return mfma_sel(a, b, c, 0);
}

__device__ __forceinline__ float wave_sum(float v) {
#pragma unroll
    for (int o = 32; o; o >>= 1) v += __shfl_xor(v, o);
    return v;
}

// ---------- constants ----------
#define HIDDEN 2880
#define NTOK 2048
#define QKV_DIM 5120
#define ATTN_DIM 4096
#define SM_SCALE 0.125f

// ---------- fp32 -> bf16 bulk convert (dual source in one launch) ----------
__global__ __launch_bounds__(256) void f32_to_bf16_dual_kernel(const float* __restrict__ a,
                                                               ushort_t* __restrict__ ao, int na8,
                                                               const float* __restrict__ b,
                                                               ushort_t* __restrict__ bo, int nb8) {
    int idx = blockIdx.x * 256 + threadIdx.x;
    if (idx < na8) {
        *(uint4v*)(ao + (size_t)idx * 8) = ld8f32_bf(a + (size_t)idx * 8);
    } else {
        int j = idx - na8;
        if (j < nb8) *(uint4v*)(bo + (size_t)j * 8) = ld8f32_bf(b + (size_t)j * 8);
    }
}

// ---------- RMSNorm: fp32 x -> bf16 normed ----------
__global__ __launch_bounds__(256) void rmsnorm_kernel(const float* __restrict__ x,
                                                      const float* __restrict__ wgt,
                                                      ushort_t* __restrict__ out) {
    const int tok = blockIdx.x, tid = threadIdx.x;
    const float* xr = x + (size_t)tok * HIDDEN;
    float v[16];
    float ss = 0.f;
#pragma unroll
    for (int i = 0; i < 2; ++i) {
        int c = tid + i * 256;
        if (c < 360) {
            float4v a = *(const float4v*)(xr + c * 8);
            float4v b = *(const float4v*)(xr + c * 8 + 4);
#pragma unroll
            for (int j = 0; j < 4; ++j) { v[i * 8 + j] = a[j]; v[i * 8 + 4 + j] = b[j]; }
#pragma unroll
            for (int j = 0; j < 8; ++j) ss += v[i * 8 + j] * v[i * 8 + j];
        }
    }
    ss = wave_sum(ss);
    __shared__ float red[4];
    if ((tid & 63) == 0) red[tid >> 6] = ss;
    __syncthreads();
    float scale = rsqrtf((red[0] + red[1] + red[2] + red[3]) * (1.f / 2880.f) + 1e-5f);
#pragma unroll
    for (int i = 0; i < 2; ++i) {
        int c = tid + i * 256;
        if (c < 360) {
            float4v wa = *(const float4v*)(wgt + c * 8);
            float4v wb = *(const float4v*)(wgt + c * 8 + 4);
            ushort_t r[8];
#pragma unroll
            for (int j = 0; j < 4; ++j) {
                r[j] = f2bf(v[i * 8 + j] * scale * wa[j]);
                r[4 + j] = f2bf(v[i * 8 + 4 + j] * scale * wb[j]);
            }
            *(uint4v*)(out + (size_t)tok * HIDDEN + c * 8) = pack8(r);
        }
    }
}

// ---------- RoPE apply, YaRN cos/sin on the fly ----------
__global__ __launch_bounds__(256) void rope_apply_kernel(ushort_t* __restrict__ qkv) {
    int idx = blockIdx.x * 256 + threadIdx.x;  // 2048 * 72 * 4
    int tok = idx / 288;
    int rem = idx - tok * 288;
    int h = rem >> 2, dg = rem & 3;
    int s = tok & 1023;
    size_t base = (size_t)tok * QKV_DIM + (h < 64 ? h * 64 : 4096 + (h - 64) * 64) + dg * 8;
    uint4v u1 = *(const uint4v*)(qkv + base);
    uint4v u2 = *(const uint4v*)(qkv + base + 32);
    float f1[8], f2[8];
    unpack8(u1, f1);
    unpack8(u2, f2);
    const float step = (float)(11.918390573078392 / 32.0);
    const float conc = (float)(1.3465735902799727);
    const float low = (float)(8.092890725542669);
    const float invden = (float)(1.0 / 9.305804387286162);
    ushort_t r1[8], r2[8];
#pragma unroll
    for (int jj = 0; jj < 8; ++jj) {
        int j = dg * 8 + jj;
        float invf = __expf(-(float)j * step);
        float ramp = ((float)j - low) * invden;
        float mask = 1.f - fminf(fmaxf(ramp, 0.f), 1.f);
        float inv_freq = invf * ((1.f - mask) * 0.03125f + mask);
        float ang = (float)s * inv_freq;
        float c = cosf(ang) * conc;
        float sn = sinf(ang) * conc;
        r1[jj] = f2bf(f1[jj] * c - f2[jj] * sn);
        r2[jj] = f2bf(f2[jj] * c + f1[jj] * sn);
    }
    *(uint4v*)(qkv + base) = pack8(r1);
    *(uint4v*)(qkv + base + 32) = pack8(r2);
}

// ---------- GEMM: C[M,N] = A[M,K](bf16) @ B[N,K]^T + bias (+ resid) ----------
// Blocks: flattened id XCD-swizzled (T1, bijective since nwg%8==0 for all grids here):
//   each XCD gets a contiguous N-fast chunk -> A-panel L2 reuse within the XCD.
// Grid-residency rule (r3 lesson): at 2 blocks/CU capacity (512 slots), prefer grids
//   just under a multiple of 512. GEMM1: 512 (100%); GEMM2: BN=96 -> 480 (93.75%);
//   BN=128-pad's 384 (75%) measured SLOWER despite better per-barrier amortization.
// GL path (BF16B + global_load_lds): double-buffered LDS, ONE barrier per K-iter
//   (proven schedule: issue async tile k+1 -> buf^1, compute tile k, barrier; the
//   compiler's vmcnt drain at the barrier lands after the compute phase). Counted-vmcnt
//   2-barrier variant measured -17% at this geometry (r2) - do not reintroduce.
//   XOR chunk swizzle (p = c ^ (row&7)) -> 0 bank conflicts.
// Fallback: padded LDS + register prefetch (round-5 structure).
template <int BN, bool RESID, bool OUTF32, bool BF16B>
__global__ __launch_bounds__(256) void gemm_kernel(const ushort_t* __restrict__ A,
                                                   const void* __restrict__ B,
                                                   const float* __restrict__ bias,
                                                   const float* __restrict__ resid,
                                                   void* __restrict__ Cout, int M, int N, int K) {
    constexpr int BM = 128, BK = 64;
    constexpr bool GL = BF16B && (HAVE_GLDS != 0);
    constexpr int LDT = GL ? 64 : 72;
    constexpr int NBUF = GL ? 2 : 1;
    static_assert(BN == 160 || BN == 128 || BN == 96 || BN == 64, "");
    __shared__ __align__(16) ushort_t As[NBUF][BM * LDT];
    __shared__ __align__(16) ushort_t Bs[NBUF][BN * LDT];

    // XCD-aware chunked swizzle of the flattened block id (nwg % 8 == 0 for all grids)
    const int nbx = gridDim.x;
    int wg = blockIdx.y * nbx + blockIdx.x;
    {
        const int nwg = nbx * gridDim.y;
        const int cpx = nwg >> 3;
        wg = (wg & 7) * cpx + (wg >> 3);
    }
    const int m0 = (wg / nbx) * BM;
    const int n0 = (wg % nbx) * BN;
    const int tid = threadIdx.x;
    const int w = tid >> 6, lane = tid & 63;
    const int quad = lane >> 4, l16 = lane & 15;

    constexpr int WN = BN / 2;
    constexpr int NI = WN / 16;  // 5 / 4 / 3 / 2
    const int wm = (w >> 1) * 64;
    const int wn = (w & 1) * WN;

    float4v acc[4][NI];
#pragma unroll
    for (int i = 0; i < 4; ++i)
#pragma unroll
        for (int j = 0; j < NI; ++j) acc[i][j] = (float4v){0.f, 0.f, 0.f, 0.f};

    const int nk = K / BK;

#if HAVE_GLDS
    if constexpr (GL) {
        constexpr int NAI = BM / 32;  // glds issues per wave for A
        constexpr int NBI = BN / 32;  // glds issues per wave for B
        const ushort_t* Bp = (const ushort_t*)B;
        const ushort_t* agp[NAI];
        const ushort_t* bgp[NBI];
        ushort_t* alp[2][NAI];
        ushort_t* blp[2][NBI];
#pragma unroll
        for (int i = 0; i < NAI; ++i) {
            int sb = (w * NAI + i) * 64;
            int s = sb + lane, r = s >> 3, p = s & 7, c = p ^ (r & 7);
            agp[i] = A + (size_t)(m0 + r) * K + c * 8;
            alp[0][i] = &As[0][sb * 8];
            alp[1][i] = &As[1][sb * 8];
        }
#pragma unroll
        for (int i = 0; i < NBI; ++i) {
            int sb = (w * NBI + i) * 64;
            int s = sb + lane, r = s >> 3, p = s & 7, c = p ^ (r & 7);
            bgp[i] = Bp + (size_t)(n0 + r) * K + c * 8;
            blp[0][i] = &Bs[0][sb * 8];
            blp[1][i] = &Bs[1][sb * 8];
        }
        // prologue: tile 0 -> buf 0
#pragma unroll
        for (int i = 0; i < NAI; ++i) glds16(agp[i], alp[0][i]);
#pragma unroll
        for (int i = 0; i < NBI; ++i) glds16(bgp[i], blp[0][i]);
        __syncthreads();

        for (int kt = 0; kt < nk; ++kt) {
            const int cur = kt & 1;
            if (kt + 1 < nk) {
                const int k0 = (kt + 1) * BK;
#pragma unroll
                for (int i = 0; i < NAI; ++i) glds16(agp[i] + k0, alp[cur ^ 1][i]);
#pragma unroll
                for (int i = 0; i < NBI; ++i) glds16(bgp[i] + k0, blp[cur ^ 1][i]);
            }
            const ushort_t* Asb = As[cur];
            const ushort_t* Bsb = Bs[cur];
#pragma unroll
            for (int ks = 0; ks < 2; ++ks) {
                short8 af[4], bfr[NI];
#pragma unroll
                for (int mi = 0; mi < 4; ++mi) {
                    int row = wm + mi * 16 + l16;
                    af[mi] = *(const short8*)(Asb + row * LDT + ((ks * 4 + quad) ^ (row & 7)) * 8);
                }
#pragma unroll
                for (int ni = 0; ni < NI; ++ni) {
                    int row = wn + ni * 16 + l16;
                    bfr[ni] = *(const short8*)(Bsb + row * LDT + ((ks * 4 + quad) ^ (row & 7)) * 8);
                }
#pragma unroll
                for (int mi = 0; mi < 4; ++mi)
#pragma unroll
                    for (int ni = 0; ni < NI; ++ni)
                        acc[mi][ni] = mfma_bf16(af[mi], bfr[ni], acc[mi][ni]);
            }
            __syncthreads();
        }
    } else
#endif
    {
        // fallback: padded LDS + register prefetch (round-5 structure)
        constexpr int ACH = BM * BK / 8 / 256;
        constexpr int BCH = BN * BK / 8 / 256;
        uint4v areg[ACH], breg[BCH];
#pragma unroll
        for (int i = 0; i < ACH; ++i) {
            int c = tid + i * 256, r = c >> 3, col = c & 7;
            areg[i] = *(const uint4v*)(A + (size_t)(m0 + r) * K + col * 8);
        }
#pragma unroll
        for (int i = 0; i < BCH; ++i) {
            int c = tid + i * 256, r = c >> 3, col = c & 7;
            if constexpr (BF16B)
                breg[i] = *(const uint4v*)((const ushort_t*)B + (size_t)(n0 + r) * K + col * 8);
            else
                breg[i] = ld8f32_bf((const float*)B + (size_t)(n0 + r) * K + col * 8);
        }
        for (int kt = 0; kt < nk; ++kt) {
            __syncthreads();
#pragma unroll
            for (int i = 0; i < ACH; ++i) {
                int c = tid + i * 256, r = c >> 3, col = c & 7;
                *(uint4v*)(&As[0][r * LDT + col * 8]) = areg[i];
            }
#pragma unroll
            for (int i = 0; i < BCH; ++i) {
                int c = tid + i * 256, r = c >> 3, col = c & 7;
                *(uint4v*)(&Bs[0][r * LDT + col * 8]) = breg[i];
            }
            __syncthreads();
            if (kt + 1 < nk) {
                const int k0 = (kt + 1) * BK;
#pragma unroll
                for (int i = 0; i < ACH; ++i) {
                    int c = tid + i * 256, r = c >> 3, col = c & 7;
                    areg[i] = *(const uint4v*)(A + (size_t)(m0 + r) * K + k0 + col * 8);
                }
#pragma unroll
                for (int i = 0; i < BCH; ++i) {
                    int c = tid + i * 256, r = c >> 3, col = c & 7;
                    if constexpr (BF16B)
                        breg[i] = *(const uint4v*)((const ushort_t*)B + (size_t)(n0 + r) * K + k0 + col * 8);
                    else
                        breg[i] = ld8f32_bf((const float*)B + (size_t)(n0 + r) * K + k0 + col * 8);
                }
            }
#pragma unroll
            for (int ks = 0; ks < 2; ++ks) {
                short8 af[4], bfr[NI];
#pragma unroll
                for (int mi = 0; mi < 4; ++mi)
                    af[mi] = *(const short8*)(&As[0][(wm + mi * 16 + l16) * LDT + ks * 32 + quad * 8]);
#pragma unroll
                for (int ni = 0; ni < NI; ++ni)
                    bfr[ni] = *(const short8*)(&Bs[0][(wn + ni * 16 + l16) * LDT + ks * 32 + quad * 8]);
#pragma unroll
                for (int mi = 0; mi < 4; ++mi)
#pragma unroll
                    for (int ni = 0; ni < NI; ++ni)
                        acc[mi][ni] = mfma_bf16(af[mi], bfr[ni], acc[mi][ni]);
            }
        }
    }

    // epilogue: C/D layout col = lane&15, row = quad*4 + reg
#pragma unroll
    for (int ni = 0; ni < NI; ++ni) {
        int gc = n0 + wn + ni * 16 + l16;
        float bv = bias[gc];
#pragma unroll
        for (int mi = 0; mi < 4; ++mi) {
#pragma unroll
            for (int r = 0; r < 4; ++r) {
                int gr = m0 + wm + mi * 16 + quad * 4 + r;
                float vv = acc[mi][ni][r] + bv;
                if constexpr (RESID) vv += resid[(size_t)gr * N + gc];
                if constexpr (OUTF32) ((float*)Cout)[(size_t)gr * N + gc] = vv;
                else ((ushort_t*)Cout)[(size_t)gr * N + gc] = f2bf(vv);
            }
        }
    }
}

// ---------- MFMA attention: sliding window 128 + sink ----------
// Grid (qc 16, kvh*2+half 16, b 2) = 512 blocks, 2 blocks/CU (157.7KB LDS).
// Wave w handles head kvh*8 + half*4 + w, 4 query-tiles of 16.
// Window-aware compute (r4): for q-tile at rows [qtile*16, qtile*16+15], valid keys
//   (causal + 128-window) span LDS rows [qtile*16, qtile*16+142] = key-tiles
//   qtile..qtile+8 (9 of 12) and PV slices kt = (qtile>>1)..(qtile>>1)+4 (5 of 6).
//   One extra P tile (ntz) is zero-filled so the PV k-range reads only defined data.
__global__ __launch_bounds__(256, 2) void attn_mfma_kernel(const ushort_t* __restrict__ qkv,
                                                           const float* __restrict__ sinks,
                                                           ushort_t* __restrict__ attnbuf) {
    constexpr int LDK = 72, LDV = 200, LDP = 200;
    __shared__ __align__(16) ushort_t Ks[192 * LDK];
    __shared__ __align__(16) ushort_t Vt[64 * LDV];
    __shared__ __align__(16) ushort_t Pb[4][16 * LDP];

    const int qc = blockIdx.x, kvh = blockIdx.y >> 1, half = blockIdx.y & 1, b = blockIdx.z;
    const int tid = threadIdx.x;
    const int w = tid >> 6, lane = tid & 63;
    const int quad = lane >> 4, l16 = lane & 15;
    const int w0 = qc * 64 - 127;  // key position of LDS row 0

    for (int c = tid; c < 192 * 8; c += 256) {
        int row = c >> 3, col8 = c & 7;
        int pos = w0 + row;
        pos = pos < 0 ? 0 : (pos > 1023 ? 1023 : pos);
        size_t gk = ((size_t)(b * 1024 + pos)) * QKV_DIM + 4096 + kvh * 64 + col8 * 8;
        *(uint4v*)(Ks + row * LDK + col8 * 8) = *(const uint4v*)(qkv + gk);
        uint4v vv = *(const uint4v*)(qkv + gk + 512);
        ushort_t vs[8];
#pragma unroll
        for (int i = 0; i < 4; ++i) {
            vs[2 * i] = (ushort_t)(vv[i] & 0xffffu);
            vs[2 * i + 1] = (ushort_t)(vv[i] >> 16);
        }
#pragma unroll
        for (int j = 0; j < 8; ++j) Vt[(col8 * 8 + j) * LDV + row] = vs[j];
    }
    __syncthreads();

    // hoist V B-fragments: k = kt*32+quad*8+j, dim = nv*16+l16
    short8 Vf[6][4];
#pragma unroll
    for (int kt = 0; kt < 6; ++kt)
#pragma unroll
        for (int nv = 0; nv < 4; ++nv)
            Vf[kt][nv] = *(const short8*)(Vt + (nv * 16 + l16) * LDV + kt * 32 + quad * 8);

    ushort_t* Pw = Pb[w];
    const int h = kvh * 8 + half * 4 + w;
    const float sink_f = sinks[h];

#pragma unroll
    for (int qtile = 0; qtile < 4; ++qtile) {
        const int tokb = b * 1024 + qc * 64 + qtile * 16;

        short8 qf[2];
        {
            const ushort_t* qp = qkv + ((size_t)(tokb + l16)) * QKV_DIM + h * 64 + quad * 8;
            qf[0] = *(const short8*)qp;
            qf[1] = *(const short8*)(qp + 32);
        }

        // QK^T over the 9 valid key-tiles (nt = qtile + j)
        float4v acc[9];
#pragma unroll
        for (int j = 0; j < 9; ++j) acc[j] = (float4v){0.f, 0.f, 0.f, 0.f};
#pragma unroll
        for (int j = 0; j < 9; ++j) {
            const int nt = qtile + j;
#pragma unroll
            for (int ks = 0; ks < 2; ++ks) {
                short8 kf = *(const short8*)(Ks + (nt * 16 + l16) * LDK + ks * 32 + quad * 8);
                acc[j] = mfma_bf16(qf[ks], kf, acc[j]);
            }
        }

        // P tile to zero-fill so PV's kt range reads only written-or-zeroed data:
        // PV covers nt in [2*(qtile>>1), 2*(qtile>>1)+9]; written are qtile..qtile+8.
        const int ntz = (qtile & 1) ? (qtile - 1) : (qtile + 9);

        float linv[4];
#pragma unroll
        for (int r = 0; r < 4; ++r) {
            const int ql = qtile * 16 + quad * 4 + r;
            float e[9];
            float mx = -1e30f;
#pragma unroll
            for (int j = 0; j < 9; ++j) {
                int row_k = (qtile + j) * 16 + l16;
                bool valid = (row_k >= ql) && (row_k <= ql + 127) && (w0 + row_k >= 0);
                float s = valid ? acc[j][r] * SM_SCALE : -1e30f;
                e[j] = s;
                mx = fmaxf(mx, s);
            }
#pragma unroll
            for (int o = 1; o < 16; o <<= 1) mx = fmaxf(mx, __shfl_xor(mx, o));
            float M = fmaxf(mx, sink_f);
            float ls = 0.f;
#pragma unroll
            for (int j = 0; j < 9; ++j) {
                float ev = (e[j] > -1e29f) ? __expf(e[j] - M) : 0.f;
                e[j] = ev;
                ls += ev;
            }
#pragma unroll
            for (int o = 1; o < 16; o <<= 1) ls += __shfl_xor(ls, o);
            linv[r] = 1.f / (ls + __expf(sink_f - M));
#pragma unroll
            for (int j = 0; j < 9; ++j)
                Pw[(quad * 4 + r) * LDP + (qtile + j) * 16 + l16] = f2bf(e[j]);
            Pw[(quad * 4 + r) * LDP + ntz * 16 + l16] = 0;
        }

        // PV over the 5 valid k-slices (kt = (qtile>>1) + j)
        float4v accO[4];
#pragma unroll
        for (int nv = 0; nv < 4; ++nv) accO[nv] = (float4v){0.f, 0.f, 0.f, 0.f};
#pragma unroll
        for (int j = 0; j < 5; ++j) {
            const int kt = (qtile >> 1) + j;
            short8 pf = *(const short8*)(Pw + l16 * LDP + kt * 32 + quad * 8);
#pragma unroll
            for (int nv = 0; nv < 4; ++nv) accO[nv] = mfma_bf16(pf, Vf[kt][nv], accO[nv]);
        }

#pragma unroll
        for (int r = 0; r < 4; ++r) {
            size_t ob = ((size_t)(tokb + quad * 4 + r)) * ATTN_DIM + h * 64 + l16;
#pragma unroll
            for (int nv = 0; nv < 4; ++nv)
                attnbuf[ob + nv * 16] = f2bf(accO[nv][r] * linv[r]);
        }
    }
}

// ---------- launch ----------
extern "C" void kernel_launch(void* const* d_in, const int* in_sizes, int n_in,
                              void* d_out, int out_size, void* d_ws, size_t ws_size,
                              hipStream_t stream) {
    const float* x = (const float*)d_in[0];
    const float* norm_w = (const float*)d_in[1];
    const float* qkv_w = (const float*)d_in[2];
    const float* qkv_b = (const float*)d_in[3];
    const float* out_w = (const float*)d_in[4];
    const float* out_b = (const float*)d_in[5];
    const float* sinks = (const float*)d_in[6];
    float* outp = (float*)d_out;
    char* ws = (char*)d_ws;

    if (ws_size >= 86000000ull) {
        // ws: qkvbuf 21MB | {qkv_w_bf 29.5MB -> attnbuf 16.8MB} | out_w_bf 23.6MB
        // Tbuf lives in d_out (dead before GEMM2 overwrites d_out).
        ushort_t* qkvbuf = (ushort_t*)ws;
        ushort_t* qkv_w_bf = (ushort_t*)(ws + 20971520);
        ushort_t* attnbuf = (ushort_t*)(ws + 20971520);  // reuse after gemm1 consumed qkv_w_bf
        ushort_t* out_w_bf = (ushort_t*)(ws + 50462720);
        ushort_t* Tbuf = (ushort_t*)d_out;

        f32_to_bf16_dual_kernel<<<12960, 256, 0, stream>>>(qkv_w, qkv_w_bf, 1843200,
                                                           out_w, out_w_bf, 1474560);
        rmsnorm_kernel<<<NTOK, 256, 0, stream>>>(x, norm_w, Tbuf);
        gemm_kernel<160, false, false, true><<<dim3(32, 16), 256, 0, stream>>>(
            Tbuf, qkv_w_bf, qkv_b, nullptr, qkvbuf, NTOK, QKV_DIM, HIDDEN);
        rope_apply_kernel<<<2304, 256, 0, stream>>>(qkvbuf);
        attn_mfma_kernel<<<dim3(16, 16, 2), 256, 0, stream>>>(qkvbuf, sinks, attnbuf);
        gemm_kernel<96, true, true, true><<<dim3(30, 16), 256, 0, stream>>>(
            attnbuf, out_w_bf, out_b, x, outp, NTOK, HIDDEN, ATTN_DIM);
    } else {
        // fallback: fp32 B loads (register staging), Tbuf in d_out
        ushort_t* qkvbuf = (ushort_t*)ws;
        ushort_t* attnbuf = (ushort_t*)(ws + 20971520);
        ushort_t* Tbuf = (ushort_t*)d_out;

        rmsnorm_kernel<<<NTOK, 256, 0, stream>>>(x, norm_w, Tbuf);
        gemm_kernel<128, false, false, false><<<dim3(40, 16), 256, 0, stream>>>(
            Tbuf, qkv_w, qkv_b, nullptr, qkvbuf, NTOK, QKV_DIM, HIDDEN);
        rope_apply_kernel<<<2304, 256, 0, stream>>>(qkvbuf);
        attn_mfma_kernel<<<dim3(16, 16, 2), 256, 0, stream>>>(qkvbuf, sinks, attnbuf);
        gemm_kernel<96, true, true, false><<<dim3(30, 16), 256, 0, stream>>>(
            attnbuf, out_w, out_b, x, outp, NTOK, HIDDEN, ATTN_DIM);
    }
}

// Round 5
// 315.026 us; speedup vs baseline: 1.0784x; 1.0056x over previous
//
#include <hip/hip_runtime.h>

typedef unsigned short ushort_t;
typedef __attribute__((ext_vector_type(8))) short short8;
typedef __attribute__((ext_vector_type(8))) __bf16 bf16x8;
typedef __attribute__((ext_vector_type(4))) float float4v;
typedef __attribute__((ext_vector_type(4))) unsigned int uint4v;

// ---------- bf16 helpers ----------
__device__ __forceinline__ float bf2f(ushort_t u) {
    unsigned int v = ((unsigned int)u) << 16;
    return __builtin_bit_cast(float, v);
}
__device__ __forceinline__ ushort_t f2bf(float f) {
    unsigned int u = __builtin_bit_cast(unsigned int, f);
    unsigned int lsb = (u >> 16) & 1u;
    u += 0x7fffu + lsb;  // round-to-nearest-even
    return (ushort_t)(u >> 16);
}
__device__ __forceinline__ uint4v pack8(const ushort_t* r) {
    uint4v u;
#pragma unroll
    for (int i = 0; i < 4; ++i)
        u[i] = (unsigned int)r[2 * i] | ((unsigned int)r[2 * i + 1] << 16);
    return u;
}
__device__ __forceinline__ void unpack8(uint4v u, float* f) {
#pragma unroll
    for (int i = 0; i < 4; ++i) {
        unsigned int x = u[i];
        f[2 * i] = __builtin_bit_cast(float, x << 16);
        f[2 * i + 1] = __builtin_bit_cast(float, x & 0xffff0000u);
    }
}
__device__ __forceinline__ uint4v ld8f32_bf(const float* p) {
    float4v a = *(const float4v*)p;
    float4v b = *(const float4v*)(p + 4);
    ushort_t r[8];
#pragma unroll
    for (int j = 0; j < 4; ++j) { r[j] = f2bf(a[j]); r[4 + j] = f2bf(b[j]); }
    return pack8(r);
}

// ---------- async global->LDS (16B per lane, dest = uniform base + lane*16) ----------
#if __has_builtin(__builtin_amdgcn_global_load_lds)
#define HAVE_GLDS 1
__device__ __forceinline__ void glds16(const ushort_t* gp, ushort_t* lp) {
    __builtin_amdgcn_global_load_lds((const __attribute__((address_space(1))) void*)gp,
                                     (__attribute__((address_space(3))) void*)lp, 16, 0, 0);
}
#else
#define HAVE_GLDS 0
#endif

// ---------- MFMA hedge ----------
template <typename V>
__device__ __forceinline__ auto mfma_sel(V a, V b, float4v c, int)
    -> decltype(__builtin_amdgcn_mfma_f32_16x16x32_bf16(a, b, c, 0, 0, 0)) {
    return __builtin_amdgcn_mfma_f32_16x16x32_bf16(a, b, c, 0, 0, 0);
}
template <typename V>
__device__ __forceinline__ float4v mfma_sel(V a, V b, float4v c, long) {
    return __builtin_amdgcn_mfma_f32_16x16x32_bf16(__builtin_bit_cast(bf16x8, a),
                                                   __builtin_bit_cast(bf16x8, b), c, 0, 0, 0);
}
__device__ __forceinline__ float4v mfma_bf16(short8 a, short8 b, float4v c) {
    return mfma_sel(a, b, c, 0);
}

__device__ __forceinline__ float wave_sum(float v) {
#pragma unroll
    for (int o = 32; o; o >>= 1) v += __shfl_xor(v, o);
    return v;
}

// ---------- constants ----------
#define HIDDEN 2880
#define NTOK 2048
#define QKV_DIM 5120
#define ATTN_DIM 4096
#define SM_SCALE 0.125f

// ---------- fp32 -> bf16 bulk convert (dual source in one launch) ----------
__global__ __launch_bounds__(256) void f32_to_bf16_dual_kernel(const float* __restrict__ a,
                                                               ushort_t* __restrict__ ao, int na8,
                                                               const float* __restrict__ b,
                                                               ushort_t* __restrict__ bo, int nb8) {
    int idx = blockIdx.x * 256 + threadIdx.x;
    if (idx < na8) {
        *(uint4v*)(ao + (size_t)idx * 8) = ld8f32_bf(a + (size_t)idx * 8);
    } else {
        int j = idx - na8;
        if (j < nb8) *(uint4v*)(bo + (size_t)j * 8) = ld8f32_bf(b + (size_t)j * 8);
    }
}

// ---------- RMSNorm: fp32 x -> bf16 normed ----------
__global__ __launch_bounds__(256) void rmsnorm_kernel(const float* __restrict__ x,
                                                      const float* __restrict__ wgt,
                                                      ushort_t* __restrict__ out) {
    const int tok = blockIdx.x, tid = threadIdx.x;
    const float* xr = x + (size_t)tok * HIDDEN;
    float v[16];
    float ss = 0.f;
#pragma unroll
    for (int i = 0; i < 2; ++i) {
        int c = tid + i * 256;
        if (c < 360) {
            float4v a = *(const float4v*)(xr + c * 8);
            float4v b = *(const float4v*)(xr + c * 8 + 4);
#pragma unroll
            for (int j = 0; j < 4; ++j) { v[i * 8 + j] = a[j]; v[i * 8 + 4 + j] = b[j]; }
#pragma unroll
            for (int j = 0; j < 8; ++j) ss += v[i * 8 + j] * v[i * 8 + j];
        }
    }
    ss = wave_sum(ss);
    __shared__ float red[4];
    if ((tid & 63) == 0) red[tid >> 6] = ss;
    __syncthreads();
    float scale = rsqrtf((red[0] + red[1] + red[2] + red[3]) * (1.f / 2880.f) + 1e-5f);
#pragma unroll
    for (int i = 0; i < 2; ++i) {
        int c = tid + i * 256;
        if (c < 360) {
            float4v wa = *(const float4v*)(wgt + c * 8);
            float4v wb = *(const float4v*)(wgt + c * 8 + 4);
            ushort_t r[8];
#pragma unroll
            for (int j = 0; j < 4; ++j) {
                r[j] = f2bf(v[i * 8 + j] * scale * wa[j]);
                r[4 + j] = f2bf(v[i * 8 + 4 + j] * scale * wb[j]);
            }
            *(uint4v*)(out + (size_t)tok * HIDDEN + c * 8) = pack8(r);
        }
    }
}

// ---------- RoPE apply, YaRN cos/sin on the fly ----------
// __sinf/__cosf (v_sin/v_cos): angle <= ~1024 rad -> rev-conversion error ~1e-5 rev
// -> sin error ~6e-5, three orders below the bf16 output quantum (~4e-3). libm
// sinf/cosf's Payne-Hanek reduction (~100+ cyc) was the kernel's VALU floor.
__global__ __launch_bounds__(256) void rope_apply_kernel(ushort_t* __restrict__ qkv) {
    int idx = blockIdx.x * 256 + threadIdx.x;  // 2048 * 72 * 4
    int tok = idx / 288;
    int rem = idx - tok * 288;
    int h = rem >> 2, dg = rem & 3;
    int s = tok & 1023;
    size_t base = (size_t)tok * QKV_DIM + (h < 64 ? h * 64 : 4096 + (h - 64) * 64) + dg * 8;
    uint4v u1 = *(const uint4v*)(qkv + base);
    uint4v u2 = *(const uint4v*)(qkv + base + 32);
    float f1[8], f2[8];
    unpack8(u1, f1);
    unpack8(u2, f2);
    const float step = (float)(11.918390573078392 / 32.0);
    const float conc = (float)(1.3465735902799727);
    const float low = (float)(8.092890725542669);
    const float invden = (float)(1.0 / 9.305804387286162);
    ushort_t r1[8], r2[8];
#pragma unroll
    for (int jj = 0; jj < 8; ++jj) {
        int j = dg * 8 + jj;
        float invf = __expf(-(float)j * step);
        float ramp = ((float)j - low) * invden;
        float mask = 1.f - fminf(fmaxf(ramp, 0.f), 1.f);
        float inv_freq = invf * ((1.f - mask) * 0.03125f + mask);
        float ang = (float)s * inv_freq;
        float c = __cosf(ang) * conc;
        float sn = __sinf(ang) * conc;
        r1[jj] = f2bf(f1[jj] * c - f2[jj] * sn);
        r2[jj] = f2bf(f2[jj] * c + f1[jj] * sn);
    }
    *(uint4v*)(qkv + base) = pack8(r1);
    *(uint4v*)(qkv + base + 32) = pack8(r2);
}

// ---------- GEMM: C[M,N] = A[M,K](bf16) @ B[N,K]^T + bias (+ resid) ----------
// Blocks: flattened id XCD-swizzled (T1, bijective since nwg%8==0 for all grids here):
//   each XCD gets a contiguous N-fast chunk -> A-panel L2 reuse within the XCD.
// Grid-residency rule (r3 lesson): at 2 blocks/CU capacity (512 slots), prefer grids
//   just under a multiple of 512. GEMM1: 512 (100%); GEMM2: BN=96 -> 480 (93.75%);
//   BN=128-pad's 384 (75%) measured SLOWER despite better per-barrier amortization.
// GL path (BF16B + global_load_lds): double-buffered LDS, ONE barrier per K-iter
//   (proven schedule: issue async tile k+1 -> buf^1, compute tile k, barrier; the
//   compiler's vmcnt drain at the barrier lands after the compute phase). Counted-vmcnt
//   2-barrier variant measured -17% at this geometry (r2) - do not reintroduce.
//   XOR chunk swizzle (p = c ^ (row&7)) -> 0 bank conflicts.
// Fallback: padded LDS + register prefetch (round-5 structure).
template <int BN, bool RESID, bool OUTF32, bool BF16B>
__global__ __launch_bounds__(256) void gemm_kernel(const ushort_t* __restrict__ A,
                                                   const void* __restrict__ B,
                                                   const float* __restrict__ bias,
                                                   const float* __restrict__ resid,
                                                   void* __restrict__ Cout, int M, int N, int K) {
    constexpr int BM = 128, BK = 64;
    constexpr bool GL = BF16B && (HAVE_GLDS != 0);
    constexpr int LDT = GL ? 64 : 72;
    constexpr int NBUF = GL ? 2 : 1;
    static_assert(BN == 160 || BN == 128 || BN == 96 || BN == 64, "");
    __shared__ __align__(16) ushort_t As[NBUF][BM * LDT];
    __shared__ __align__(16) ushort_t Bs[NBUF][BN * LDT];

    // XCD-aware chunked swizzle of the flattened block id (nwg % 8 == 0 for all grids)
    const int nbx = gridDim.x;
    int wg = blockIdx.y * nbx + blockIdx.x;
    {
        const int nwg = nbx * gridDim.y;
        const int cpx = nwg >> 3;
        wg = (wg & 7) * cpx + (wg >> 3);
    }
    const int m0 = (wg / nbx) * BM;
    const int n0 = (wg % nbx) * BN;
    const int tid = threadIdx.x;
    const int w = tid >> 6, lane = tid & 63;
    const int quad = lane >> 4, l16 = lane & 15;

    constexpr int WN = BN / 2;
    constexpr int NI = WN / 16;  // 5 / 4 / 3 / 2
    const int wm = (w >> 1) * 64;
    const int wn = (w & 1) * WN;

    float4v acc[4][NI];
#pragma unroll
    for (int i = 0; i < 4; ++i)
#pragma unroll
        for (int j = 0; j < NI; ++j) acc[i][j] = (float4v){0.f, 0.f, 0.f, 0.f};

    const int nk = K / BK;

#if HAVE_GLDS
    if constexpr (GL) {
        constexpr int NAI = BM / 32;  // glds issues per wave for A
        constexpr int NBI = BN / 32;  // glds issues per wave for B
        const ushort_t* Bp = (const ushort_t*)B;
        const ushort_t* agp[NAI];
        const ushort_t* bgp[NBI];
        ushort_t* alp[2][NAI];
        ushort_t* blp[2][NBI];
#pragma unroll
        for (int i = 0; i < NAI; ++i) {
            int sb = (w * NAI + i) * 64;
            int s = sb + lane, r = s >> 3, p = s & 7, c = p ^ (r & 7);
            agp[i] = A + (size_t)(m0 + r) * K + c * 8;
            alp[0][i] = &As[0][sb * 8];
            alp[1][i] = &As[1][sb * 8];
        }
#pragma unroll
        for (int i = 0; i < NBI; ++i) {
            int sb = (w * NBI + i) * 64;
            int s = sb + lane, r = s >> 3, p = s & 7, c = p ^ (r & 7);
            bgp[i] = Bp + (size_t)(n0 + r) * K + c * 8;
            blp[0][i] = &Bs[0][sb * 8];
            blp[1][i] = &Bs[1][sb * 8];
        }
        // prologue: tile 0 -> buf 0
#pragma unroll
        for (int i = 0; i < NAI; ++i) glds16(agp[i], alp[0][i]);
#pragma unroll
        for (int i = 0; i < NBI; ++i) glds16(bgp[i], blp[0][i]);
        __syncthreads();

        for (int kt = 0; kt < nk; ++kt) {
            const int cur = kt & 1;
            if (kt + 1 < nk) {
                const int k0 = (kt + 1) * BK;
#pragma unroll
                for (int i = 0; i < NAI; ++i) glds16(agp[i] + k0, alp[cur ^ 1][i]);
#pragma unroll
                for (int i = 0; i < NBI; ++i) glds16(bgp[i] + k0, blp[cur ^ 1][i]);
            }
            const ushort_t* Asb = As[cur];
            const ushort_t* Bsb = Bs[cur];
#pragma unroll
            for (int ks = 0; ks < 2; ++ks) {
                short8 af[4], bfr[NI];
#pragma unroll
                for (int mi = 0; mi < 4; ++mi) {
                    int row = wm + mi * 16 + l16;
                    af[mi] = *(const short8*)(Asb + row * LDT + ((ks * 4 + quad) ^ (row & 7)) * 8);
                }
#pragma unroll
                for (int ni = 0; ni < NI; ++ni) {
                    int row = wn + ni * 16 + l16;
                    bfr[ni] = *(const short8*)(Bsb + row * LDT + ((ks * 4 + quad) ^ (row & 7)) * 8);
                }
#pragma unroll
                for (int mi = 0; mi < 4; ++mi)
#pragma unroll
                    for (int ni = 0; ni < NI; ++ni)
                        acc[mi][ni] = mfma_bf16(af[mi], bfr[ni], acc[mi][ni]);
            }
            __syncthreads();
        }
    } else
#endif
    {
        // fallback: padded LDS + register prefetch (round-5 structure)
        constexpr int ACH = BM * BK / 8 / 256;
        constexpr int BCH = BN * BK / 8 / 256;
        uint4v areg[ACH], breg[BCH];
#pragma unroll
        for (int i = 0; i < ACH; ++i) {
            int c = tid + i * 256, r = c >> 3, col = c & 7;
            areg[i] = *(const uint4v*)(A + (size_t)(m0 + r) * K + col * 8);
        }
#pragma unroll
        for (int i = 0; i < BCH; ++i) {
            int c = tid + i * 256, r = c >> 3, col = c & 7;
            if constexpr (BF16B)
                breg[i] = *(const uint4v*)((const ushort_t*)B + (size_t)(n0 + r) * K + col * 8);
            else
                breg[i] = ld8f32_bf((const float*)B + (size_t)(n0 + r) * K + col * 8);
        }
        for (int kt = 0; kt < nk; ++kt) {
            __syncthreads();
#pragma unroll
            for (int i = 0; i < ACH; ++i) {
                int c = tid + i * 256, r = c >> 3, col = c & 7;
                *(uint4v*)(&As[0][r * LDT + col * 8]) = areg[i];
            }
#pragma unroll
            for (int i = 0; i < BCH; ++i) {
                int c = tid + i * 256, r = c >> 3, col = c & 7;
                *(uint4v*)(&Bs[0][r * LDT + col * 8]) = breg[i];
            }
            __syncthreads();
            if (kt + 1 < nk) {
                const int k0 = (kt + 1) * BK;
#pragma unroll
                for (int i = 0; i < ACH; ++i) {
                    int c = tid + i * 256, r = c >> 3, col = c & 7;
                    areg[i] = *(const uint4v*)(A + (size_t)(m0 + r) * K + k0 + col * 8);
                }
#pragma unroll
                for (int i = 0; i < BCH; ++i) {
                    int c = tid + i * 256, r = c >> 3, col = c & 7;
                    if constexpr (BF16B)
                        breg[i] = *(const uint4v*)((const ushort_t*)B + (size_t)(n0 + r) * K + k0 + col * 8);
                    else
                        breg[i] = ld8f32_bf((const float*)B + (size_t)(n0 + r) * K + k0 + col * 8);
                }
            }
#pragma unroll
            for (int ks = 0; ks < 2; ++ks) {
                short8 af[4], bfr[NI];
#pragma unroll
                for (int mi = 0; mi < 4; ++mi)
                    af[mi] = *(const short8*)(&As[0][(wm + mi * 16 + l16) * LDT + ks * 32 + quad * 8]);
#pragma unroll
                for (int ni = 0; ni < NI; ++ni)
                    bfr[ni] = *(const short8*)(&Bs[0][(wn + ni * 16 + l16) * LDT + ks * 32 + quad * 8]);
#pragma unroll
                for (int mi = 0; mi < 4; ++mi)
#pragma unroll
                    for (int ni = 0; ni < NI; ++ni)
                        acc[mi][ni] = mfma_bf16(af[mi], bfr[ni], acc[mi][ni]);
            }
        }
    }

    // epilogue: C/D layout col = lane&15, row = quad*4 + reg
#pragma unroll
    for (int ni = 0; ni < NI; ++ni) {
        int gc = n0 + wn + ni * 16 + l16;
        float bv = bias[gc];
#pragma unroll
        for (int mi = 0; mi < 4; ++mi) {
#pragma unroll
            for (int r = 0; r < 4; ++r) {
                int gr = m0 + wm + mi * 16 + quad * 4 + r;
                float vv = acc[mi][ni][r] + bv;
                if constexpr (RESID) vv += resid[(size_t)gr * N + gc];
                if constexpr (OUTF32) ((float*)Cout)[(size_t)gr * N + gc] = vv;
                else ((ushort_t*)Cout)[(size_t)gr * N + gc] = f2bf(vv);
            }
        }
    }
}

// ---------- MFMA attention: sliding window 128 + sink ----------
// Grid (qc 16, kvh*2+half 16, b 2) = 512 blocks, 2 blocks/CU (157.7KB LDS).
// Wave w handles head kvh*8 + half*4 + w, 4 query-tiles of 16.
// Window-aware compute: for q-tile rows [qtile*16, qtile*16+15], valid keys span
//   key-tiles qtile..qtile+8 (9 of 12) and PV slices kt = (qtile>>1)..(qtile>>1)+4.
// Pair structure (r5): q-tiles (2p, 2p+1) share the PV slice set kt = p..p+4, so the
//   outer loop runs over p (ROLLED, halves code size) hoisting Vf[5][4] (80 VGPR,
//   freed between pairs); the 2 inner q-tiles are unrolled with static reg indexing
//   (rule #20). r4's full 4x unroll + Vf[6][4] (96 VGPR always-live) ran at the
//   256-VGPR launch-bounds edge and gave back the window savings.
__global__ __launch_bounds__(256, 2) void attn_mfma_kernel(const ushort_t* __restrict__ qkv,
                                                           const float* __restrict__ sinks,
                                                           ushort_t* __restrict__ attnbuf) {
    constexpr int LDK = 72, LDV = 200, LDP = 200;
    __shared__ __align__(16) ushort_t Ks[192 * LDK];
    __shared__ __align__(16) ushort_t Vt[64 * LDV];
    __shared__ __align__(16) ushort_t Pb[4][16 * LDP];

    const int qc = blockIdx.x, kvh = blockIdx.y >> 1, half = blockIdx.y & 1, b = blockIdx.z;
    const int tid = threadIdx.x;
    const int w = tid >> 6, lane = tid & 63;
    const int quad = lane >> 4, l16 = lane & 15;
    const int w0 = qc * 64 - 127;  // key position of LDS row 0

    for (int c = tid; c < 192 * 8; c += 256) {
        int row = c >> 3, col8 = c & 7;
        int pos = w0 + row;
        pos = pos < 0 ? 0 : (pos > 1023 ? 1023 : pos);
        size_t gk = ((size_t)(b * 1024 + pos)) * QKV_DIM + 4096 + kvh * 64 + col8 * 8;
        *(uint4v*)(Ks + row * LDK + col8 * 8) = *(const uint4v*)(qkv + gk);
        uint4v vv = *(const uint4v*)(qkv + gk + 512);
        ushort_t vs[8];
#pragma unroll
        for (int i = 0; i < 4; ++i) {
            vs[2 * i] = (ushort_t)(vv[i] & 0xffffu);
            vs[2 * i + 1] = (ushort_t)(vv[i] >> 16);
        }
#pragma unroll
        for (int j = 0; j < 8; ++j) Vt[(col8 * 8 + j) * LDV + row] = vs[j];
    }
    __syncthreads();

    ushort_t* Pw = Pb[w];
    const int h = kvh * 8 + half * 4 + w;
    const float sink_f = sinks[h];

    for (int p = 0; p < 2; ++p) {  // q-tile pair: q-tiles 2p, 2p+1 share PV kt = p..p+4
        // hoist V B-fragments for this pair: k = (p+j)*32+quad*8, dim = nv*16+l16
        short8 Vf[5][4];
#pragma unroll
        for (int j = 0; j < 5; ++j)
#pragma unroll
            for (int nv = 0; nv < 4; ++nv)
                Vf[j][nv] = *(const short8*)(Vt + (nv * 16 + l16) * LDV + (p + j) * 32 + quad * 8);

#pragma unroll
        for (int qq = 0; qq < 2; ++qq) {
            const int qtile = 2 * p + qq;
            const int tokb = b * 1024 + qc * 64 + qtile * 16;

            short8 qf[2];
            {
                const ushort_t* qp = qkv + ((size_t)(tokb + l16)) * QKV_DIM + h * 64 + quad * 8;
                qf[0] = *(const short8*)qp;
                qf[1] = *(const short8*)(qp + 32);
            }

            // QK^T over the 9 valid key-tiles (nt = qtile + j)
            float4v acc[9];
#pragma unroll
            for (int j = 0; j < 9; ++j) acc[j] = (float4v){0.f, 0.f, 0.f, 0.f};
            __builtin_amdgcn_s_setprio(1);
#pragma unroll
            for (int j = 0; j < 9; ++j) {
                const int nt = qtile + j;
#pragma unroll
                for (int ks = 0; ks < 2; ++ks) {
                    short8 kf = *(const short8*)(Ks + (nt * 16 + l16) * LDK + ks * 32 + quad * 8);
                    acc[j] = mfma_bf16(qf[ks], kf, acc[j]);
                }
            }
            __builtin_amdgcn_s_setprio(0);

            // P tile to zero so PV's nt range [2p, 2p+9] reads only written/zeroed data:
            // qq=0 writes [2p,2p+8] -> zero 2p+9; qq=1 writes [2p+1,2p+9] -> zero 2p.
            const int ntz = qq ? (qtile - 1) : (qtile + 9);

            float linv[4];
#pragma unroll
            for (int r = 0; r < 4; ++r) {
                const int ql = qtile * 16 + quad * 4 + r;
                float e[9];
                float mx = -1e30f;
#pragma unroll
                for (int j = 0; j < 9; ++j) {
                    int row_k = (qtile + j) * 16 + l16;
                    bool valid = (row_k >= ql) && (row_k <= ql + 127) && (w0 + row_k >= 0);
                    float s = valid ? acc[j][r] * SM_SCALE : -1e30f;
                    e[j] = s;
                    mx = fmaxf(mx, s);
                }
#pragma unroll
                for (int o = 1; o < 16; o <<= 1) mx = fmaxf(mx, __shfl_xor(mx, o));
                float M = fmaxf(mx, sink_f);
                float ls = 0.f;
#pragma unroll
                for (int j = 0; j < 9; ++j) {
                    float ev = (e[j] > -1e29f) ? __expf(e[j] - M) : 0.f;
                    e[j] = ev;
                    ls += ev;
                }
#pragma unroll
                for (int o = 1; o < 16; o <<= 1) ls += __shfl_xor(ls, o);
                linv[r] = 1.f / (ls + __expf(sink_f - M));
#pragma unroll
                for (int j = 0; j < 9; ++j)
                    Pw[(quad * 4 + r) * LDP + (qtile + j) * 16 + l16] = f2bf(e[j]);
                Pw[(quad * 4 + r) * LDP + ntz * 16 + l16] = 0;
            }

            // PV over the 5 valid k-slices (kt = p + j, matching Vf[j])
            float4v accO[4];
#pragma unroll
            for (int nv = 0; nv < 4; ++nv) accO[nv] = (float4v){0.f, 0.f, 0.f, 0.f};
            __builtin_amdgcn_s_setprio(1);
#pragma unroll
            for (int j = 0; j < 5; ++j) {
                short8 pf = *(const short8*)(Pw + l16 * LDP + (p + j) * 32 + quad * 8);
#pragma unroll
                for (int nv = 0; nv < 4; ++nv) accO[nv] = mfma_bf16(pf, Vf[j][nv], accO[nv]);
            }
            __builtin_amdgcn_s_setprio(0);

#pragma unroll
            for (int r = 0; r < 4; ++r) {
                size_t ob = ((size_t)(tokb + quad * 4 + r)) * ATTN_DIM + h * 64 + l16;
#pragma unroll
                for (int nv = 0; nv < 4; ++nv)
                    attnbuf[ob + nv * 16] = f2bf(accO[nv][r] * linv[r]);
            }
        }
    }
}

// ---------- launch ----------
extern "C" void kernel_launch(void* const* d_in, const int* in_sizes, int n_in,
                              void* d_out, int out_size, void* d_ws, size_t ws_size,
                              hipStream_t stream) {
    const float* x = (const float*)d_in[0];
    const float* norm_w = (const float*)d_in[1];
    const float* qkv_w = (const float*)d_in[2];
    const float* qkv_b = (const float*)d_in[3];
    const float* out_w = (const float*)d_in[4];
    const float* out_b = (const float*)d_in[5];
    const float* sinks = (const float*)d_in[6];
    float* outp = (float*)d_out;
    char* ws = (char*)d_ws;

    if (ws_size >= 86000000ull) {
        // ws: qkvbuf 21MB | {qkv_w_bf 29.5MB -> attnbuf 16.8MB} | out_w_bf 23.6MB
        // Tbuf lives in d_out (dead before GEMM2 overwrites d_out).
        ushort_t* qkvbuf = (ushort_t*)ws;
        ushort_t* qkv_w_bf = (ushort_t*)(ws + 20971520);
        ushort_t* attnbuf = (ushort_t*)(ws + 20971520);  // reuse after gemm1 consumed qkv_w_bf
        ushort_t* out_w_bf = (ushort_t*)(ws + 50462720);
        ushort_t* Tbuf = (ushort_t*)d_out;

        f32_to_bf16_dual_kernel<<<12960, 256, 0, stream>>>(qkv_w, qkv_w_bf, 1843200,
                                                           out_w, out_w_bf, 1474560);
        rmsnorm_kernel<<<NTOK, 256, 0, stream>>>(x, norm_w, Tbuf);
        gemm_kernel<160, false, false, true><<<dim3(32, 16), 256, 0, stream>>>(
            Tbuf, qkv_w_bf, qkv_b, nullptr, qkvbuf, NTOK, QKV_DIM, HIDDEN);
        rope_apply_kernel<<<2304, 256, 0, stream>>>(qkvbuf);
        attn_mfma_kernel<<<dim3(16, 16, 2), 256, 0, stream>>>(qkvbuf, sinks, attnbuf);
        gemm_kernel<96, true, true, true><<<dim3(30, 16), 256, 0, stream>>>(
            attnbuf, out_w_bf, out_b, x, outp, NTOK, HIDDEN, ATTN_DIM);
    } else {
        // fallback: fp32 B loads (register staging), Tbuf in d_out
        ushort_t* qkvbuf = (ushort_t*)ws;
        ushort_t* attnbuf = (ushort_t*)(ws + 20971520);
        ushort_t* Tbuf = (ushort_t*)d_out;

        rmsnorm_kernel<<<NTOK, 256, 0, stream>>>(x, norm_w, Tbuf);
        gemm_kernel<128, false, false, false><<<dim3(40, 16), 256, 0, stream>>>(
            Tbuf, qkv_w, qkv_b, nullptr, qkvbuf, NTOK, QKV_DIM, HIDDEN);
        rope_apply_kernel<<<2304, 256, 0, stream>>>(qkvbuf);
        attn_mfma_kernel<<<dim3(16, 16, 2), 256, 0, stream>>>(qkvbuf, sinks, attnbuf);
        gemm_kernel<96, true, true, false><<<dim3(30, 16), 256, 0, stream>>>(
            attnbuf, out_w, out_b, x, outp, NTOK, HIDDEN, ATTN_DIM);
    }
}

// Round 6
// 308.657 us; speedup vs baseline: 1.1006x; 1.0206x over previous
//
#include <hip/hip_runtime.h>

typedef unsigned short ushort_t;
typedef __attribute__((ext_vector_type(8))) short short8;
typedef __attribute__((ext_vector_type(8))) __bf16 bf16x8;
typedef __attribute__((ext_vector_type(4))) float float4v;
typedef __attribute__((ext_vector_type(4))) unsigned int uint4v;

// ---------- bf16 helpers ----------
__device__ __forceinline__ float bf2f(ushort_t u) {
    unsigned int v = ((unsigned int)u) << 16;
    return __builtin_bit_cast(float, v);
}
__device__ __forceinline__ ushort_t f2bf(float f) {
    unsigned int u = __builtin_bit_cast(unsigned int, f);
    unsigned int lsb = (u >> 16) & 1u;
    u += 0x7fffu + lsb;  // round-to-nearest-even
    return (ushort_t)(u >> 16);
}
__device__ __forceinline__ uint4v pack8(const ushort_t* r) {
    uint4v u;
#pragma unroll
    for (int i = 0; i < 4; ++i)
        u[i] = (unsigned int)r[2 * i] | ((unsigned int)r[2 * i + 1] << 16);
    return u;
}
__device__ __forceinline__ void unpack8(uint4v u, float* f) {
#pragma unroll
    for (int i = 0; i < 4; ++i) {
        unsigned int x = u[i];
        f[2 * i] = __builtin_bit_cast(float, x << 16);
        f[2 * i + 1] = __builtin_bit_cast(float, x & 0xffff0000u);
    }
}
__device__ __forceinline__ uint4v ld8f32_bf(const float* p) {
    float4v a = *(const float4v*)p;
    float4v b = *(const float4v*)(p + 4);
    ushort_t r[8];
#pragma unroll
    for (int j = 0; j < 4; ++j) { r[j] = f2bf(a[j]); r[4 + j] = f2bf(b[j]); }
    return pack8(r);
}

// ---------- async global->LDS (16B per lane, dest = uniform base + lane*16) ----------
#if __has_builtin(__builtin_amdgcn_global_load_lds)
#define HAVE_GLDS 1
__device__ __forceinline__ void glds16(const ushort_t* gp, ushort_t* lp) {
    __builtin_amdgcn_global_load_lds((const __attribute__((address_space(1))) void*)gp,
                                     (__attribute__((address_space(3))) void*)lp, 16, 0, 0);
}
#else
#define HAVE_GLDS 0
#endif

// ---------- MFMA hedge ----------
template <typename V>
__device__ __forceinline__ auto mfma_sel(V a, V b, float4v c, int)
    -> decltype(__builtin_amdgcn_mfma_f32_16x16x32_bf16(a, b, c, 0, 0, 0)) {
    return __builtin_amdgcn_mfma_f32_16x16x32_bf16(a, b, c, 0, 0, 0);
}
template <typename V>
__device__ __forceinline__ float4v mfma_sel(V a, V b, float4v c, long) {
    return __builtin_amdgcn_mfma_f32_16x16x32_bf16(__builtin_bit_cast(bf16x8, a),
                                                   __builtin_bit_cast(bf16x8, b), c, 0, 0, 0);
}
__device__ __forceinline__ float4v mfma_bf16(short8 a, short8 b, float4v c) {
    return mfma_sel(a, b, c, 0);
}

__device__ __forceinline__ float wave_sum(float v) {
#pragma unroll
    for (int o = 32; o; o >>= 1) v += __shfl_xor(v, o);
    return v;
}

// ---------- constants ----------
#define HIDDEN 2880
#define NTOK 2048
#define QKV_DIM 5120
#define ATTN_DIM 4096
#define SM_SCALE 0.125f

// YaRN rope constants (shared by attn fused rope)
#define ROPE_STEP 0.37244970540869975f   /* 11.918390573078392 / 32 */
#define ROPE_CONC 1.3465735902799727f
#define ROPE_LOW 8.092890725542669f
#define ROPE_INVDEN 0.10745959154836568f /* 1 / 9.305804387286162 */

__device__ __forceinline__ float rope_invfreq(int j) {
    float invf = __expf(-(float)j * ROPE_STEP);
    float ramp = ((float)j - ROPE_LOW) * ROPE_INVDEN;
    float mask = 1.f - fminf(fmaxf(ramp, 0.f), 1.f);
    return invf * ((1.f - mask) * 0.03125f + mask);
}

// ---------- prep: rmsnorm (blocks 0..2047) + fp32->bf16 weight convert (rest) ----------
__global__ __launch_bounds__(256) void prep_kernel(const float* __restrict__ x,
                                                   const float* __restrict__ wgt,
                                                   ushort_t* __restrict__ tout,
                                                   const float* __restrict__ a,
                                                   ushort_t* __restrict__ ao, int na8,
                                                   const float* __restrict__ b,
                                                   ushort_t* __restrict__ bo, int nb8) {
    const int tid = threadIdx.x;
    __shared__ float red[4];
    if (blockIdx.x < NTOK) {
        // ---- RMSNorm for token blockIdx.x ----
        const int tok = blockIdx.x;
        const float* xr = x + (size_t)tok * HIDDEN;
        float v[16];
        float ss = 0.f;
#pragma unroll
        for (int i = 0; i < 2; ++i) {
            int c = tid + i * 256;
            if (c < 360) {
                float4v va = *(const float4v*)(xr + c * 8);
                float4v vb = *(const float4v*)(xr + c * 8 + 4);
#pragma unroll
                for (int j = 0; j < 4; ++j) { v[i * 8 + j] = va[j]; v[i * 8 + 4 + j] = vb[j]; }
#pragma unroll
                for (int j = 0; j < 8; ++j) ss += v[i * 8 + j] * v[i * 8 + j];
            }
        }
        ss = wave_sum(ss);
        if ((tid & 63) == 0) red[tid >> 6] = ss;
        __syncthreads();
        float scale = rsqrtf((red[0] + red[1] + red[2] + red[3]) * (1.f / 2880.f) + 1e-5f);
#pragma unroll
        for (int i = 0; i < 2; ++i) {
            int c = tid + i * 256;
            if (c < 360) {
                float4v wa = *(const float4v*)(wgt + c * 8);
                float4v wb = *(const float4v*)(wgt + c * 8 + 4);
                ushort_t r[8];
#pragma unroll
                for (int j = 0; j < 4; ++j) {
                    r[j] = f2bf(v[i * 8 + j] * scale * wa[j]);
                    r[4 + j] = f2bf(v[i * 8 + 4 + j] * scale * wb[j]);
                }
                *(uint4v*)(tout + (size_t)tok * HIDDEN + c * 8) = pack8(r);
            }
        }
    } else {
        // ---- weight conversion ----
        int idx = (blockIdx.x - NTOK) * 256 + tid;
        if (idx < na8) {
            *(uint4v*)(ao + (size_t)idx * 8) = ld8f32_bf(a + (size_t)idx * 8);
        } else {
            int j = idx - na8;
            if (j < nb8) *(uint4v*)(bo + (size_t)j * 8) = ld8f32_bf(b + (size_t)j * 8);
        }
    }
}

// ---------- RMSNorm standalone (fallback path) ----------
__global__ __launch_bounds__(256) void rmsnorm_kernel(const float* __restrict__ x,
                                                      const float* __restrict__ wgt,
                                                      ushort_t* __restrict__ out) {
    const int tok = blockIdx.x, tid = threadIdx.x;
    const float* xr = x + (size_t)tok * HIDDEN;
    float v[16];
    float ss = 0.f;
#pragma unroll
    for (int i = 0; i < 2; ++i) {
        int c = tid + i * 256;
        if (c < 360) {
            float4v a = *(const float4v*)(xr + c * 8);
            float4v b = *(const float4v*)(xr + c * 8 + 4);
#pragma unroll
            for (int j = 0; j < 4; ++j) { v[i * 8 + j] = a[j]; v[i * 8 + 4 + j] = b[j]; }
#pragma unroll
            for (int j = 0; j < 8; ++j) ss += v[i * 8 + j] * v[i * 8 + j];
        }
    }
    ss = wave_sum(ss);
    __shared__ float red[4];
    if ((tid & 63) == 0) red[tid >> 6] = ss;
    __syncthreads();
    float scale = rsqrtf((red[0] + red[1] + red[2] + red[3]) * (1.f / 2880.f) + 1e-5f);
#pragma unroll
    for (int i = 0; i < 2; ++i) {
        int c = tid + i * 256;
        if (c < 360) {
            float4v wa = *(const float4v*)(wgt + c * 8);
            float4v wb = *(const float4v*)(wgt + c * 8 + 4);
            ushort_t r[8];
#pragma unroll
            for (int j = 0; j < 4; ++j) {
                r[j] = f2bf(v[i * 8 + j] * scale * wa[j]);
                r[4 + j] = f2bf(v[i * 8 + 4 + j] * scale * wb[j]);
            }
            *(uint4v*)(out + (size_t)tok * HIDDEN + c * 8) = pack8(r);
        }
    }
}

// ---------- GEMM: C[M,N] = A[M,K](bf16) @ B[N,K]^T + bias (+ resid) ----------
// Blocks: flattened id XCD-swizzled (T1, bijective since nwg%8==0 for all grids here):
//   each XCD gets a contiguous N-fast chunk -> A-panel L2 reuse within the XCD.
// Grid-residency rule (r3): at 2 blocks/CU capacity (512 slots), prefer grids just
//   under a multiple of 512. GEMM1: 512; GEMM2: BN=96 -> 480. BN=128-pad (384, 75%)
//   and BN=160-GEMM2 (288 -> 56% busy) are worse despite better per-barrier ratios.
// LDS-BW model (r5): per CU per K-step, 8 waves x (4+NI) ds_read_b128 x2; NI=3 is
//   ds-read-bound (~896 cy vs 754 cy MFMA), NI=5 is MFMA-bound. N=2880 forces NI=3.
// GL path: double-buffered LDS, ONE barrier per K-iter (proven schedule). Counted-
//   vmcnt 2-barrier variant measured -17% at this geometry (r2) - do not reintroduce.
//   XOR chunk swizzle (p = c ^ (row&7)) -> 0 bank conflicts.
template <int BN, bool RESID, bool OUTF32, bool BF16B>
__global__ __launch_bounds__(256) void gemm_kernel(const ushort_t* __restrict__ A,
                                                   const void* __restrict__ B,
                                                   const float* __restrict__ bias,
                                                   const float* __restrict__ resid,
                                                   void* __restrict__ Cout, int M, int N, int K) {
    constexpr int BM = 128, BK = 64;
    constexpr bool GL = BF16B && (HAVE_GLDS != 0);
    constexpr int LDT = GL ? 64 : 72;
    constexpr int NBUF = GL ? 2 : 1;
    static_assert(BN == 160 || BN == 128 || BN == 96 || BN == 64, "");
    __shared__ __align__(16) ushort_t As[NBUF][BM * LDT];
    __shared__ __align__(16) ushort_t Bs[NBUF][BN * LDT];

    // XCD-aware chunked swizzle of the flattened block id (nwg % 8 == 0 for all grids)
    const int nbx = gridDim.x;
    int wg = blockIdx.y * nbx + blockIdx.x;
    {
        const int nwg = nbx * gridDim.y;
        const int cpx = nwg >> 3;
        wg = (wg & 7) * cpx + (wg >> 3);
    }
    const int m0 = (wg / nbx) * BM;
    const int n0 = (wg % nbx) * BN;
    const int tid = threadIdx.x;
    const int w = tid >> 6, lane = tid & 63;
    const int quad = lane >> 4, l16 = lane & 15;

    constexpr int WN = BN / 2;
    constexpr int NI = WN / 16;  // 5 / 4 / 3 / 2
    const int wm = (w >> 1) * 64;
    const int wn = (w & 1) * WN;

    float4v acc[4][NI];
#pragma unroll
    for (int i = 0; i < 4; ++i)
#pragma unroll
        for (int j = 0; j < NI; ++j) acc[i][j] = (float4v){0.f, 0.f, 0.f, 0.f};

    const int nk = K / BK;

#if HAVE_GLDS
    if constexpr (GL) {
        constexpr int NAI = BM / 32;  // glds issues per wave for A
        constexpr int NBI = BN / 32;  // glds issues per wave for B
        const ushort_t* Bp = (const ushort_t*)B;
        const ushort_t* agp[NAI];
        const ushort_t* bgp[NBI];
        ushort_t* alp[2][NAI];
        ushort_t* blp[2][NBI];
#pragma unroll
        for (int i = 0; i < NAI; ++i) {
            int sb = (w * NAI + i) * 64;
            int s = sb + lane, r = s >> 3, p = s & 7, c = p ^ (r & 7);
            agp[i] = A + (size_t)(m0 + r) * K + c * 8;
            alp[0][i] = &As[0][sb * 8];
            alp[1][i] = &As[1][sb * 8];
        }
#pragma unroll
        for (int i = 0; i < NBI; ++i) {
            int sb = (w * NBI + i) * 64;
            int s = sb + lane, r = s >> 3, p = s & 7, c = p ^ (r & 7);
            bgp[i] = Bp + (size_t)(n0 + r) * K + c * 8;
            blp[0][i] = &Bs[0][sb * 8];
            blp[1][i] = &Bs[1][sb * 8];
        }
        // prologue: tile 0 -> buf 0
#pragma unroll
        for (int i = 0; i < NAI; ++i) glds16(agp[i], alp[0][i]);
#pragma unroll
        for (int i = 0; i < NBI; ++i) glds16(bgp[i], blp[0][i]);
        __syncthreads();

        for (int kt = 0; kt < nk; ++kt) {
            const int cur = kt & 1;
            if (kt + 1 < nk) {
                const int k0 = (kt + 1) * BK;
#pragma unroll
                for (int i = 0; i < NAI; ++i) glds16(agp[i] + k0, alp[cur ^ 1][i]);
#pragma unroll
                for (int i = 0; i < NBI; ++i) glds16(bgp[i] + k0, blp[cur ^ 1][i]);
            }
            const ushort_t* Asb = As[cur];
            const ushort_t* Bsb = Bs[cur];
#pragma unroll
            for (int ks = 0; ks < 2; ++ks) {
                short8 af[4], bfr[NI];
#pragma unroll
                for (int mi = 0; mi < 4; ++mi) {
                    int row = wm + mi * 16 + l16;
                    af[mi] = *(const short8*)(Asb + row * LDT + ((ks * 4 + quad) ^ (row & 7)) * 8);
                }
#pragma unroll
                for (int ni = 0; ni < NI; ++ni) {
                    int row = wn + ni * 16 + l16;
                    bfr[ni] = *(const short8*)(Bsb + row * LDT + ((ks * 4 + quad) ^ (row & 7)) * 8);
                }
#pragma unroll
                for (int mi = 0; mi < 4; ++mi)
#pragma unroll
                    for (int ni = 0; ni < NI; ++ni)
                        acc[mi][ni] = mfma_bf16(af[mi], bfr[ni], acc[mi][ni]);
            }
            __syncthreads();
        }
    } else
#endif
    {
        // fallback: padded LDS + register prefetch (round-5 structure)
        constexpr int ACH = BM * BK / 8 / 256;
        constexpr int BCH = BN * BK / 8 / 256;
        uint4v areg[ACH], breg[BCH];
#pragma unroll
        for (int i = 0; i < ACH; ++i) {
            int c = tid + i * 256, r = c >> 3, col = c & 7;
            areg[i] = *(const uint4v*)(A + (size_t)(m0 + r) * K + col * 8);
        }
#pragma unroll
        for (int i = 0; i < BCH; ++i) {
            int c = tid + i * 256, r = c >> 3, col = c & 7;
            if constexpr (BF16B)
                breg[i] = *(const uint4v*)((const ushort_t*)B + (size_t)(n0 + r) * K + col * 8);
            else
                breg[i] = ld8f32_bf((const float*)B + (size_t)(n0 + r) * K + col * 8);
        }
        for (int kt = 0; kt < nk; ++kt) {
            __syncthreads();
#pragma unroll
            for (int i = 0; i < ACH; ++i) {
                int c = tid + i * 256, r = c >> 3, col = c & 7;
                *(uint4v*)(&As[0][r * LDT + col * 8]) = areg[i];
            }
#pragma unroll
            for (int i = 0; i < BCH; ++i) {
                int c = tid + i * 256, r = c >> 3, col = c & 7;
                *(uint4v*)(&Bs[0][r * LDT + col * 8]) = breg[i];
            }
            __syncthreads();
            if (kt + 1 < nk) {
                const int k0 = (kt + 1) * BK;
#pragma unroll
                for (int i = 0; i < ACH; ++i) {
                    int c = tid + i * 256, r = c >> 3, col = c & 7;
                    areg[i] = *(const uint4v*)(A + (size_t)(m0 + r) * K + k0 + col * 8);
                }
#pragma unroll
                for (int i = 0; i < BCH; ++i) {
                    int c = tid + i * 256, r = c >> 3, col = c & 7;
                    if constexpr (BF16B)
                        breg[i] = *(const uint4v*)((const ushort_t*)B + (size_t)(n0 + r) * K + k0 + col * 8);
                    else
                        breg[i] = ld8f32_bf((const float*)B + (size_t)(n0 + r) * K + k0 + col * 8);
                }
            }
#pragma unroll
            for (int ks = 0; ks < 2; ++ks) {
                short8 af[4], bfr[NI];
#pragma unroll
                for (int mi = 0; mi < 4; ++mi)
                    af[mi] = *(const short8*)(&As[0][(wm + mi * 16 + l16) * LDT + ks * 32 + quad * 8]);
#pragma unroll
                for (int ni = 0; ni < NI; ++ni)
                    bfr[ni] = *(const short8*)(&Bs[0][(wn + ni * 16 + l16) * LDT + ks * 32 + quad * 8]);
#pragma unroll
                for (int mi = 0; mi < 4; ++mi)
#pragma unroll
                    for (int ni = 0; ni < NI; ++ni)
                        acc[mi][ni] = mfma_bf16(af[mi], bfr[ni], acc[mi][ni]);
            }
        }
    }

    // epilogue: C/D layout col = lane&15, row = quad*4 + reg
#pragma unroll
    for (int ni = 0; ni < NI; ++ni) {
        int gc = n0 + wn + ni * 16 + l16;
        float bv = bias[gc];
#pragma unroll
        for (int mi = 0; mi < 4; ++mi) {
#pragma unroll
            for (int r = 0; r < 4; ++r) {
                int gr = m0 + wm + mi * 16 + quad * 4 + r;
                float vv = acc[mi][ni][r] + bv;
                if constexpr (RESID) vv += resid[(size_t)gr * N + gc];
                if constexpr (OUTF32) ((float*)Cout)[(size_t)gr * N + gc] = vv;
                else ((ushort_t*)Cout)[(size_t)gr * N + gc] = f2bf(vv);
            }
        }
    }
}

// ---------- MFMA attention: sliding window 128 + sink, RoPE fused on load ----------
// Grid (qc 16, kvh*2+half 16, b 2) = 512 blocks, 2 blocks/CU (157.7KB LDS).
// Wave w handles head kvh*8 + half*4 + w, 4 query-tiles of 16.
// RoPE fusion (r6): qkvbuf is UN-roped; q/k regions are consumed only here.
//   Q: rotate-half pair (d, d+32) = (qf[0][jj], qf[1][jj]) -> same lane, rope is
//      lane-local at load; inv_freq(quad*8+jj) hoisted per lane.
//   K: staging restructured so each lane loads dims [col4*8,+8) AND [+32,+8) of one
//      row, ropes 8 pairs (inv_freq((tid&3)*8+jj) hoisted - iteration-invariant),
//      writes both 16B chunks. OOB-clamped rows get roped at clamped pos - fully
//      masked downstream. V needs no rope.
// Window-aware compute: q-tile qtile touches key-tiles qtile..qtile+8 and PV slices
//   kt = (qtile>>1)..+4. Pair structure: q-tiles (2p,2p+1) share Vf[5][4] hoist.
__global__ __launch_bounds__(256, 2) void attn_mfma_kernel(const ushort_t* __restrict__ qkv,
                                                           const float* __restrict__ sinks,
                                                           ushort_t* __restrict__ attnbuf) {
    constexpr int LDK = 72, LDV = 200, LDP = 200;
    __shared__ __align__(16) ushort_t Ks[192 * LDK];
    __shared__ __align__(16) ushort_t Vt[64 * LDV];
    __shared__ __align__(16) ushort_t Pb[4][16 * LDP];

    const int qc = blockIdx.x, kvh = blockIdx.y >> 1, half = blockIdx.y & 1, b = blockIdx.z;
    const int tid = threadIdx.x;
    const int w = tid >> 6, lane = tid & 63;
    const int quad = lane >> 4, l16 = lane & 15;
    const int w0 = qc * 64 - 127;  // key position of LDS row 0

    // K stage + rope: 3 iters; lane owns dims [col4*8,+8) and [+32,+8) of row c>>2.
    {
        float invfK[8];
#pragma unroll
        for (int jj = 0; jj < 8; ++jj) invfK[jj] = rope_invfreq((tid & 3) * 8 + jj);
        for (int c = tid; c < 192 * 4; c += 256) {
            int row = c >> 2, col4 = c & 3;
            int pos = w0 + row;
            pos = pos < 0 ? 0 : (pos > 1023 ? 1023 : pos);
            size_t gk = ((size_t)(b * 1024 + pos)) * QKV_DIM + 4096 + kvh * 64 + col4 * 8;
            uint4v u1 = *(const uint4v*)(qkv + gk);
            uint4v u2 = *(const uint4v*)(qkv + gk + 32);
            float f1[8], f2[8];
            unpack8(u1, f1);
            unpack8(u2, f2);
            float s = (float)pos;
            ushort_t r1[8], r2[8];
#pragma unroll
            for (int jj = 0; jj < 8; ++jj) {
                float ang = s * invfK[jj];
                float cc = __cosf(ang) * ROPE_CONC;
                float sn = __sinf(ang) * ROPE_CONC;
                r1[jj] = f2bf(f1[jj] * cc - f2[jj] * sn);
                r2[jj] = f2bf(f2[jj] * cc + f1[jj] * sn);
            }
            *(uint4v*)(Ks + row * LDK + col4 * 8) = pack8(r1);
            *(uint4v*)(Ks + row * LDK + (col4 + 4) * 8) = pack8(r2);
        }
    }
    // V stage (transpose), no rope
    for (int c = tid; c < 192 * 8; c += 256) {
        int row = c >> 3, col8 = c & 7;
        int pos = w0 + row;
        pos = pos < 0 ? 0 : (pos > 1023 ? 1023 : pos);
        size_t gv = ((size_t)(b * 1024 + pos)) * QKV_DIM + 4608 + kvh * 64 + col8 * 8;
        uint4v vv = *(const uint4v*)(qkv + gv);
        ushort_t vs[8];
#pragma unroll
        for (int i = 0; i < 4; ++i) {
            vs[2 * i] = (ushort_t)(vv[i] & 0xffffu);
            vs[2 * i + 1] = (ushort_t)(vv[i] >> 16);
        }
#pragma unroll
        for (int j = 0; j < 8; ++j) Vt[(col8 * 8 + j) * LDV + row] = vs[j];
    }
    __syncthreads();

    ushort_t* Pw = Pb[w];
    const int h = kvh * 8 + half * 4 + w;
    const float sink_f = sinks[h];

    // per-lane Q rope inv_freq: j = quad*8+jj
    float invfQ[8];
#pragma unroll
    for (int jj = 0; jj < 8; ++jj) invfQ[jj] = rope_invfreq(quad * 8 + jj);

    for (int p = 0; p < 2; ++p) {  // q-tile pair: q-tiles 2p, 2p+1 share PV kt = p..p+4
        short8 Vf[5][4];
#pragma unroll
        for (int j = 0; j < 5; ++j)
#pragma unroll
            for (int nv = 0; nv < 4; ++nv)
                Vf[j][nv] = *(const short8*)(Vt + (nv * 16 + l16) * LDV + (p + j) * 32 + quad * 8);

#pragma unroll
        for (int qq = 0; qq < 2; ++qq) {
            const int qtile = 2 * p + qq;
            const int tokb = b * 1024 + qc * 64 + qtile * 16;

            // Q load + lane-local rope
            short8 qf[2];
            {
                const ushort_t* qp = qkv + ((size_t)(tokb + l16)) * QKV_DIM + h * 64 + quad * 8;
                uint4v u1 = *(const uint4v*)qp;
                uint4v u2 = *(const uint4v*)(qp + 32);
                float f1[8], f2[8];
                unpack8(u1, f1);
                unpack8(u2, f2);
                float s = (float)((tokb + l16) & 1023);
                ushort_t r1[8], r2[8];
#pragma unroll
                for (int jj = 0; jj < 8; ++jj) {
                    float ang = s * invfQ[jj];
                    float cc = __cosf(ang) * ROPE_CONC;
                    float sn = __sinf(ang) * ROPE_CONC;
                    r1[jj] = f2bf(f1[jj] * cc - f2[jj] * sn);
                    r2[jj] = f2bf(f2[jj] * cc + f1[jj] * sn);
                }
                qf[0] = __builtin_bit_cast(short8, pack8(r1));
                qf[1] = __builtin_bit_cast(short8, pack8(r2));
            }

            // QK^T over the 9 valid key-tiles (nt = qtile + j)
            float4v acc[9];
#pragma unroll
            for (int j = 0; j < 9; ++j) acc[j] = (float4v){0.f, 0.f, 0.f, 0.f};
            __builtin_amdgcn_s_setprio(1);
#pragma unroll
            for (int j = 0; j < 9; ++j) {
                const int nt = qtile + j;
#pragma unroll
                for (int ks = 0; ks < 2; ++ks) {
                    short8 kf = *(const short8*)(Ks + (nt * 16 + l16) * LDK + ks * 32 + quad * 8);
                    acc[j] = mfma_bf16(qf[ks], kf, acc[j]);
                }
            }
            __builtin_amdgcn_s_setprio(0);

            // P tile to zero so PV's nt range [2p, 2p+9] reads only written/zeroed data
            const int ntz = qq ? (qtile - 1) : (qtile + 9);

            float linv[4];
#pragma unroll
            for (int r = 0; r < 4; ++r) {
                const int ql = qtile * 16 + quad * 4 + r;
                float e[9];
                float mx = -1e30f;
#pragma unroll
                for (int j = 0; j < 9; ++j) {
                    int row_k = (qtile + j) * 16 + l16;
                    bool valid = (row_k >= ql) && (row_k <= ql + 127) && (w0 + row_k >= 0);
                    float s = valid ? acc[j][r] * SM_SCALE : -1e30f;
                    e[j] = s;
                    mx = fmaxf(mx, s);
                }
#pragma unroll
                for (int o = 1; o < 16; o <<= 1) mx = fmaxf(mx, __shfl_xor(mx, o));
                float M = fmaxf(mx, sink_f);
                float ls = 0.f;
#pragma unroll
                for (int j = 0; j < 9; ++j) {
                    float ev = (e[j] > -1e29f) ? __expf(e[j] - M) : 0.f;
                    e[j] = ev;
                    ls += ev;
                }
#pragma unroll
                for (int o = 1; o < 16; o <<= 1) ls += __shfl_xor(ls, o);
                linv[r] = 1.f / (ls + __expf(sink_f - M));
#pragma unroll
                for (int j = 0; j < 9; ++j)
                    Pw[(quad * 4 + r) * LDP + (qtile + j) * 16 + l16] = f2bf(e[j]);
                Pw[(quad * 4 + r) * LDP + ntz * 16 + l16] = 0;
            }

            // PV over the 5 valid k-slices (kt = p + j, matching Vf[j])
            float4v accO[4];
#pragma unroll
            for (int nv = 0; nv < 4; ++nv) accO[nv] = (float4v){0.f, 0.f, 0.f, 0.f};
            __builtin_amdgcn_s_setprio(1);
#pragma unroll
            for (int j = 0; j < 5; ++j) {
                short8 pf = *(const short8*)(Pw + l16 * LDP + (p + j) * 32 + quad * 8);
#pragma unroll
                for (int nv = 0; nv < 4; ++nv) accO[nv] = mfma_bf16(pf, Vf[j][nv], accO[nv]);
            }
            __builtin_amdgcn_s_setprio(0);

#pragma unroll
            for (int r = 0; r < 4; ++r) {
                size_t ob = ((size_t)(tokb + quad * 4 + r)) * ATTN_DIM + h * 64 + l16;
#pragma unroll
                for (int nv = 0; nv < 4; ++nv)
                    attnbuf[ob + nv * 16] = f2bf(accO[nv][r] * linv[r]);
            }
        }
    }
}

// ---------- launch ----------
extern "C" void kernel_launch(void* const* d_in, const int* in_sizes, int n_in,
                              void* d_out, int out_size, void* d_ws, size_t ws_size,
                              hipStream_t stream) {
    const float* x = (const float*)d_in[0];
    const float* norm_w = (const float*)d_in[1];
    const float* qkv_w = (const float*)d_in[2];
    const float* qkv_b = (const float*)d_in[3];
    const float* out_w = (const float*)d_in[4];
    const float* out_b = (const float*)d_in[5];
    const float* sinks = (const float*)d_in[6];
    float* outp = (float*)d_out;
    char* ws = (char*)d_ws;

    if (ws_size >= 86000000ull) {
        // ws: qkvbuf 21MB | {qkv_w_bf 29.5MB -> attnbuf 16.8MB} | out_w_bf 23.6MB
        // Tbuf lives in d_out (dead before GEMM2 overwrites d_out).
        ushort_t* qkvbuf = (ushort_t*)ws;
        ushort_t* qkv_w_bf = (ushort_t*)(ws + 20971520);
        ushort_t* attnbuf = (ushort_t*)(ws + 20971520);  // reuse after gemm1 consumed qkv_w_bf
        ushort_t* out_w_bf = (ushort_t*)(ws + 50462720);
        ushort_t* Tbuf = (ushort_t*)d_out;

        // prep: 2048 rmsnorm blocks + 12960 conversion blocks in one launch
        prep_kernel<<<NTOK + 12960, 256, 0, stream>>>(x, norm_w, Tbuf, qkv_w, qkv_w_bf,
                                                      1843200, out_w, out_w_bf, 1474560);
        gemm_kernel<160, false, false, true><<<dim3(32, 16), 256, 0, stream>>>(
            Tbuf, qkv_w_bf, qkv_b, nullptr, qkvbuf, NTOK, QKV_DIM, HIDDEN);
        attn_mfma_kernel<<<dim3(16, 16, 2), 256, 0, stream>>>(qkvbuf, sinks, attnbuf);
        gemm_kernel<96, true, true, true><<<dim3(30, 16), 256, 0, stream>>>(
            attnbuf, out_w_bf, out_b, x, outp, NTOK, HIDDEN, ATTN_DIM);
    } else {
        // fallback: fp32 B loads (register staging), Tbuf in d_out
        ushort_t* qkvbuf = (ushort_t*)ws;
        ushort_t* attnbuf = (ushort_t*)(ws + 20971520);
        ushort_t* Tbuf = (ushort_t*)d_out;

        rmsnorm_kernel<<<NTOK, 256, 0, stream>>>(x, norm_w, Tbuf);
        gemm_kernel<128, false, false, false><<<dim3(40, 16), 256, 0, stream>>>(
            Tbuf, qkv_w, qkv_b, nullptr, qkvbuf, NTOK, QKV_DIM, HIDDEN);
        attn_mfma_kernel<<<dim3(16, 16, 2), 256, 0, stream>>>(qkvbuf, sinks, attnbuf);
        gemm_kernel<96, true, true, false><<<dim3(30, 16), 256, 0, stream>>>(
            attnbuf, out_w, out_b, x, outp, NTOK, HIDDEN, ATTN_DIM);
    }
}